// Round 1
// baseline (929.462 us; speedup 1.0000x reference)
//
#include <hip/hip_runtime.h>
#include <hip/hip_bf16.h>
#include <math.h>

// Problem constants: B=4, S=2048, H=1024, nh=16, dh=64.
#define BATCH 4
#define SEQ   2048
#define HID   1024
#define NH    16
#define DH    64
#define MTOT  (BATCH * SEQ)   // 8192
#define FILLV (-1e13f)

typedef unsigned short ushort_t;
typedef short bf16x8 __attribute__((ext_vector_type(8)));
typedef float f32x4  __attribute__((ext_vector_type(4)));

__device__ __forceinline__ float bf2f(ushort_t u) {
    return __uint_as_float(((unsigned int)u) << 16);
}
__device__ __forceinline__ ushort_t f2bf(float f) {
    union { __hip_bfloat16 h; ushort_t u; } cv;
    cv.h = __float2bfloat16(f);
    return cv.u;
}

// async global->LDS, 16B per lane; LDS dest = wave-uniform base + lane*16
__device__ __forceinline__ void gload16(const void* g, void* l) {
    __builtin_amdgcn_global_load_lds(
        (const __attribute__((address_space(1))) unsigned int*)g,
        (__attribute__((address_space(3))) unsigned int*)l, 16, 0, 0);
}

// ---------------------------------------------------------------------------
// fp32 -> bf16 cast, 4 elems/thread
// ---------------------------------------------------------------------------
__global__ __launch_bounds__(256) void cast_f32_bf16(
    const float* __restrict__ x, ushort_t* __restrict__ y, int n4)
{
    const int i = blockIdx.x * 256 + threadIdx.x;
    if (i < n4) {
        const float4 v = ((const float4*)x)[i];
        ushort4 o;
        o.x = f2bf(v.x); o.y = f2bf(v.y); o.z = f2bf(v.z); o.w = f2bf(v.w);
        ((ushort4*)y)[i] = o;
    }
}

// ---------------------------------------------------------------------------
// bf16 MFMA GEMM (m97 pattern): Y[M,N] = A[M,K] @ W[N,K]^T + bias
// 128x128 tile, BK=32, 256 threads = 4 waves (2x2 of 64x64), 16x16x32 MFMA.
// BIAS_ROW=false: bias indexed by output col (normal Linear).
// BIAS_ROW=true:  bias indexed by output row (used for Vt = Wv @ value^T).
// ---------------------------------------------------------------------------
template <bool OUT_BF16, bool BIAS_ROW>
__global__ __launch_bounds__(256) void gemm_bt_mfma(
    const ushort_t* __restrict__ A,   // [M,K] bf16
    const ushort_t* __restrict__ W,   // [N,K] bf16
    const float*    __restrict__ bias,
    void* __restrict__ Yv,            // [M,N] bf16 or fp32
    int M, int N, int K)
{
    __shared__ ushort_t As[8 * 512];  // 8 slabs x 1024B
    __shared__ ushort_t Bs[8 * 512];

    const int tid  = threadIdx.x;
    const int lane = tid & 63;
    const int wave = tid >> 6;
    const int wm   = wave & 1;
    const int wn   = wave >> 1;
    const int m0   = blockIdx.y * 128;
    const int n0   = blockIdx.x * 128;
    const int lr   = lane & 15;
    const int lk   = (lane >> 4) * 8;

    const ushort_t* aP = A + (size_t)(m0 + wave * 32 + lr) * K + lk;
    const ushort_t* wP = W + (size_t)(n0 + wave * 32 + lr) * K + lk;
    ushort_t* aL = &As[wave * 1024];
    ushort_t* bL = &Bs[wave * 1024];

    f32x4 acc[4][4];
#pragma unroll
    for (int i = 0; i < 4; i++)
#pragma unroll
        for (int j = 0; j < 4; j++) acc[i][j] = (f32x4){0.f, 0.f, 0.f, 0.f};

    for (int k0 = 0; k0 < K; k0 += 32) {
        gload16(aP,          aL);
        gload16(aP + 16 * K, aL + 512);
        gload16(wP,          bL);
        gload16(wP + 16 * K, bL + 512);
        aP += 32; wP += 32;
        __syncthreads();

        bf16x8 af[4], bf[4];
#pragma unroll
        for (int i = 0; i < 4; i++)
            af[i] = *(const bf16x8*)&As[(wm * 4 + i) * 512 + lane * 8];
#pragma unroll
        for (int j = 0; j < 4; j++)
            bf[j] = *(const bf16x8*)&Bs[(wn * 4 + j) * 512 + lane * 8];
#pragma unroll
        for (int i = 0; i < 4; i++)
#pragma unroll
            for (int j = 0; j < 4; j++)
                acc[i][j] = __builtin_amdgcn_mfma_f32_16x16x32_bf16(
                    af[i], bf[j], acc[i][j], 0, 0, 0);
        __syncthreads();
    }

    // epilogue; C/D layout: col = lane&15, row = (lane>>4)*4 + reg
    const int orow = (lane >> 4) * 4;
    const int ocol = lane & 15;

#pragma unroll
    for (int i = 0; i < 4; i++) {
#pragma unroll
        for (int j = 0; j < 4; j++) {
            const int col = n0 + wn * 64 + j * 16 + ocol;
#pragma unroll
            for (int r = 0; r < 4; r++) {
                const int row = m0 + wm * 64 + i * 16 + orow + r;
                const float bvv = BIAS_ROW ? bias[row] : bias[col];
                const float v = acc[i][j][r] + bvv;
                if (OUT_BF16)
                    ((ushort_t*)Yv)[(size_t)row * N + col] = f2bf(v);
                else
                    ((float*)Yv)[(size_t)row * N + col] = v;
            }
        }
    }
}

// ---------------------------------------------------------------------------
// MFMA flash attention, zero barriers, paired q-tiles, XCD-local K/V,
// K-fragment register double-buffer — SWAPPED-OPERAND edition.
//
//  QK^T is computed as mfma(K, Q) -> S^T in C/D (col = q = lane&15,
//  row = key = lq*4+r within tile). Each lane then owns 16 of the 64
//  scores of ONE q-row:
//    - row max  = 15 in-reg fmax + 2 shfl_xor (16,32)   [was 16 shfls]
//    - m/l/alpha are per-lane SCALARS                    [was 4-row arrays]
//    - P stored transposed to per-wave LDS with 4 packed ds_write_b64
//      (was 16 scalar b16 writes); read back as B-frags (unchanged pattern)
//    - PV computed as mfma(V, P) -> O^T (col = q, row = d) so V loads are
//      also unchanged; epilogue packs ushort4 (4 stores/tile, was 16)
//  All global-load patterns (Q,K,V frags) are IDENTICAL to the previous
//  verified kernel — only mfma operand order + index bookkeeping changed.
//  s_setprio(1) wraps both MFMA clusters (T5, +4-7% on attn per learn_hip).
// ---------------------------------------------------------------------------
__global__ __launch_bounds__(256, 4) void attn_mfma(
    const ushort_t* __restrict__ Qp,   // [B*S, H]
    const ushort_t* __restrict__ Kp,   // [B*S, H]
    const ushort_t* __restrict__ Vt,   // [H, B*S]
    const float*    __restrict__ mask, // [B, S] over key positions
    ushort_t* __restrict__ Op)         // [B*S, H]
{
    __shared__ ushort_t Pl[4][16 * 72];  // per-wave P^T: [q=16][key=64], stride 72

    const int tid  = threadIdx.x;
    const int lane = tid & 63;
    const int wave = tid >> 6;
    const int li   = lane & 15;   // frag idx | C/D col (now = q index)
    const int lq   = lane >> 4;   // quad
    const int blk  = blockIdx.x;
    // XCD-aware mapping: xcd = blk&7 (round-robin dispatch), 8 heads per XCD,
    // 16 blocks (pp=0..15) per (b,h), 4 pair-indices per block (one per wave).
    const int xcd = blk & 7;
    const int jj  = blk >> 3;            // 0..127
    const int bh  = xcd * 8 + (jj & 7);  // 0..63
    const int pp  = jj >> 3;             // 0..15
    const int pr  = pp * 4 + wave;       // 0..63: q-tiles {pr, 127-pr}
    const int h   = bh & (NH - 1);
    const int b   = bh >> 4;
    const int prow = lq * 4;      // this lane's C/D row base (now = key/d offset)

    const ushort_t* kbase = Kp + ((size_t)b * SEQ + li) * HID + (size_t)h * DH + lq * 8;
    const ushort_t* vbase = Vt + ((size_t)h * DH + li) * MTOT + (size_t)b * SEQ + lq * 8;
    const float*    mbase = mask + (size_t)b * SEQ + prow;   // indexed by key+r
    ushort_t* pw = &Pl[wave][0];

#pragma unroll
    for (int t = 0; t < 2; t++) {
        const int qt = (t == 0) ? pr : (127 - pr);
        const int q0 = qt * 16;
        const int qrow = q0 + li;            // this lane's q position

        // persistent Q B-fragments (k-chunks 0,1 of dh=64)
        const size_t qaddr = ((size_t)b * SEQ + qrow) * HID + (size_t)h * DH + lq * 8;
        const bf16x8 qf0 = *(const bf16x8*)&Qp[qaddr];
        const bf16x8 qf1 = *(const bf16x8*)&Qp[qaddr + 32];

        f32x4 oa[4];                          // O^T: oa[nt][r] = O[q=li][d=nt*16+prow+r]
#pragma unroll
        for (int nt = 0; nt < 4; nt++) oa[nt] = (f32x4){0.f, 0.f, 0.f, 0.f};
        float m_i = -1e30f, l_i = 0.f;        // per-lane scalars (one q-row each)

        const int jmax = q0 >> 6;

        // ---- preload K A-frags for j=0 ----
        bf16x8 kf[4][2];
#pragma unroll
        for (int nt = 0; nt < 4; nt++) {
            const ushort_t* kp = kbase + (size_t)(nt * 16) * HID;
            kf[nt][0] = *(const bf16x8*)kp;
            kf[nt][1] = *(const bf16x8*)(kp + 32);
        }

        for (int j = 0; j <= jmax; j++) {
            const int k0 = j * 64;

            // ---- prefetch K frags for j+1 (consumed next iter) ----
            bf16x8 kn[4][2];
            if (j < jmax) {
                const int k1 = k0 + 64;
#pragma unroll
                for (int nt = 0; nt < 4; nt++) {
                    const ushort_t* kp = kbase + (size_t)(k1 + nt * 16) * HID;
                    kn[nt][0] = *(const bf16x8*)kp;
                    kn[nt][1] = *(const bf16x8*)(kp + 32);
                }
            }

            // ---- mask for current block (8KB/batch, L1/L2-resident; load
            //      latency hides under the QK MFMAs) ----
            f32x4 mk[4];
#pragma unroll
            for (int nt = 0; nt < 4; nt++)
                mk[nt] = *(const f32x4*)&mbase[k0 + nt * 16];

            // ---- hoist V A-frag loads: latency overlaps softmax below ----
            bf16x8 vf[4][2];
#pragma unroll
            for (int nt = 0; nt < 4; nt++) {
                const ushort_t* vp = vbase + (size_t)(nt * 16) * MTOT + k0;
                vf[nt][0] = *(const bf16x8*)vp;
                vf[nt][1] = *(const bf16x8*)(vp + 32);
            }

            // ---- S^T = K Q^T (per 16-key tile nt); col=q, row=key ----
            f32x4 sa[4];
            __builtin_amdgcn_s_setprio(1);
#pragma unroll
            for (int nt = 0; nt < 4; nt++) {
                f32x4 acc = (f32x4){0.f, 0.f, 0.f, 0.f};
                acc = __builtin_amdgcn_mfma_f32_16x16x32_bf16(kf[nt][0], qf0, acc, 0, 0, 0);
                acc = __builtin_amdgcn_mfma_f32_16x16x32_bf16(kf[nt][1], qf1, acc, 0, 0, 0);
                sa[nt] = acc;
            }
            __builtin_amdgcn_s_setprio(0);

            // ---- scale + padding mask + causal mask (all branchless) ----
            float s[4][4];
#pragma unroll
            for (int nt = 0; nt < 4; nt++)
#pragma unroll
                for (int r = 0; r < 4; r++) {
                    float v = sa[nt][r] * 0.125f;
                    s[nt][r] = (mk[nt][r] == 0.f) ? FILLV : v;
                }

            if (k0 + 63 > q0) {  // wave-uniform: diagonal-straddling tiles only
#pragma unroll
                for (int nt = 0; nt < 4; nt++) {
#pragma unroll
                    for (int r = 0; r < 4; r++) {
                        const int kpos = k0 + nt * 16 + prow + r;
                        s[nt][r] = (kpos > qrow) ? FILLV : s[nt][r];
                    }
                }
            }

            // ---- online softmax: lane-local row, 15 fmax + 2 shfls ----
            float pm = fmaxf(fmaxf(s[0][0], s[0][1]), fmaxf(s[0][2], s[0][3]));
#pragma unroll
            for (int nt = 1; nt < 4; nt++)
                pm = fmaxf(pm, fmaxf(fmaxf(s[nt][0], s[nt][1]),
                                     fmaxf(s[nt][2], s[nt][3])));
            pm = fmaxf(pm, __shfl_xor(pm, 16));
            pm = fmaxf(pm, __shfl_xor(pm, 32));
            const float mnew  = fmaxf(m_i, pm);
            const float alpha = __expf(m_i - mnew);
            m_i = mnew;

            float psum = 0.f;
#pragma unroll
            for (int nt = 0; nt < 4; nt++) {
                const float p0 = __expf(s[nt][0] - mnew);
                const float p1 = __expf(s[nt][1] - mnew);
                const float p2 = __expf(s[nt][2] - mnew);
                const float p3 = __expf(s[nt][3] - mnew);
                psum += (p0 + p1) + (p2 + p3);
                ushort4 pk;
                pk.x = f2bf(p0); pk.y = f2bf(p1); pk.z = f2bf(p2); pk.w = f2bf(p3);
                // P^T slab: [q=li][key = nt*16 + prow + 0..3], packed 8B write
                *(ushort4*)&pw[li * 72 + nt * 16 + prow] = pk;
            }
            psum += __shfl_xor(psum, 16);
            psum += __shfl_xor(psum, 32);
            l_i = l_i * alpha + psum;

            // ---- rescale O^T by scalar alpha (fills LDS-write latency) ----
#pragma unroll
            for (int nt = 0; nt < 4; nt++)
#pragma unroll
                for (int r = 0; r < 4; r++) oa[nt][r] *= alpha;

            // ---- P as B-fragments (same-wave LDS RAW -> compiler lgkmcnt) ----
            const bf16x8 pf0 = *(const bf16x8*)&pw[li * 72 + lq * 8];
            const bf16x8 pf1 = *(const bf16x8*)&pw[li * 72 + 32 + lq * 8];

            // ---- O^T += V^T P^T : mfma(V, P), col=q, row=d ----
            __builtin_amdgcn_s_setprio(1);
#pragma unroll
            for (int nt = 0; nt < 4; nt++) {
                f32x4 o = oa[nt];
                o = __builtin_amdgcn_mfma_f32_16x16x32_bf16(vf[nt][0], pf0, o, 0, 0, 0);
                o = __builtin_amdgcn_mfma_f32_16x16x32_bf16(vf[nt][1], pf1, o, 0, 0, 0);
                oa[nt] = o;
            }
            __builtin_amdgcn_s_setprio(0);

            // ---- rotate K double-buffer ----
            if (j < jmax) {
#pragma unroll
                for (int nt = 0; nt < 4; nt++) {
                    kf[nt][0] = kn[nt][0];
                    kf[nt][1] = kn[nt][1];
                }
            }
        }

        // ---- normalize + packed bf16 store (4x 8B per tile) ----
        const float linv = 1.f / l_i;
        const size_t obase = ((size_t)b * SEQ + qrow) * HID + (size_t)h * DH + prow;
#pragma unroll
        for (int nt = 0; nt < 4; nt++) {
            ushort4 ov;
            ov.x = f2bf(oa[nt][0] * linv);
            ov.y = f2bf(oa[nt][1] * linv);
            ov.z = f2bf(oa[nt][2] * linv);
            ov.w = f2bf(oa[nt][3] * linv);
            *(ushort4*)&Op[obase + nt * 16] = ov;
        }
    }
}

// ---------------------------------------------------------------------------
extern "C" void kernel_launch(void* const* d_in, const int* in_sizes, int n_in,
                              void* d_out, int out_size, void* d_ws, size_t ws_size,
                              hipStream_t stream) {
    const float* query = (const float*)d_in[0];
    const float* key   = (const float*)d_in[1];
    const float* value = (const float*)d_in[2];
    const float* mask  = (const float*)d_in[3];
    const float* Wq    = (const float*)d_in[4];
    const float* bq    = (const float*)d_in[5];
    const float* Wk    = (const float*)d_in[6];
    const float* bk    = (const float*)d_in[7];
    const float* Wv    = (const float*)d_in[8];
    const float* bv    = (const float*)d_in[9];
    const float* Wo    = (const float*)d_in[10];
    const float* bo    = (const float*)d_in[11];

    // workspace (bf16): 7 activation-size buffers + 4 weight buffers ≈ 125.5 MB
    const size_t eA = (size_t)MTOT * HID;
    const size_t eW = (size_t)HID * HID;
    ushort_t* qb  = (ushort_t*)d_ws;
    ushort_t* kb  = qb  + eA;
    ushort_t* vb  = kb  + eA;
    ushort_t* Qp  = vb  + eA;
    ushort_t* Kp  = Qp  + eA;
    ushort_t* Vtb = Kp  + eA;   // [H, B*S]
    ushort_t* Op  = Vtb + eA;
    ushort_t* wqb = Op  + eA;
    ushort_t* wkb = wqb + eW;
    ushort_t* wvb = wkb + eW;
    ushort_t* wob = wvb + eW;

    const int n4a = (int)(eA / 4), n4w = (int)(eW / 4);
    cast_f32_bf16<<<(n4a + 255) / 256, 256, 0, stream>>>(query, qb, n4a);
    cast_f32_bf16<<<(n4a + 255) / 256, 256, 0, stream>>>(key,   kb, n4a);
    cast_f32_bf16<<<(n4a + 255) / 256, 256, 0, stream>>>(value, vb, n4a);
    cast_f32_bf16<<<(n4w + 255) / 256, 256, 0, stream>>>(Wq, wqb, n4w);
    cast_f32_bf16<<<(n4w + 255) / 256, 256, 0, stream>>>(Wk, wkb, n4w);
    cast_f32_bf16<<<(n4w + 255) / 256, 256, 0, stream>>>(Wv, wvb, n4w);
    cast_f32_bf16<<<(n4w + 255) / 256, 256, 0, stream>>>(Wo, wob, n4w);

    dim3 gg(HID / 128, MTOT / 128);   // (8, 64)
    gemm_bt_mfma<true, false><<<gg, 256, 0, stream>>>(qb, wqb, bq, Qp, MTOT, HID, HID);
    gemm_bt_mfma<true, false><<<gg, 256, 0, stream>>>(kb, wkb, bk, Kp, MTOT, HID, HID);
    // Vt = Wv @ value^T  -> [H, B*S], bias by row (bv[d])
    dim3 gv(MTOT / 128, HID / 128);   // (64, 8)
    gemm_bt_mfma<true, true><<<gv, 256, 0, stream>>>(wvb, vb, bv, Vtb, HID, MTOT, HID);

    // flash attention: 4096 uniform waves, XCD-local (b,h), 4 waves/block
    attn_mfma<<<(BATCH * NH * 64) / 4, 256, 0, stream>>>(Qp, Kp, Vtb, mask, Op);

    gemm_bt_mfma<false, false><<<gg, 256, 0, stream>>>(Op, wob, bo, d_out, MTOT, HID, HID);
}

// Round 2
// 575.736 us; speedup vs baseline: 1.6144x; 1.6144x over previous
//
#include <hip/hip_runtime.h>
#include <hip/hip_bf16.h>
#include <math.h>

// Problem constants: B=4, S=2048, H=1024, nh=16, dh=64.
#define BATCH 4
#define SEQ   2048
#define HID   1024
#define NH    16
#define DH    64
#define MTOT  (BATCH * SEQ)   // 8192
#define FILLV (-1e13f)

typedef unsigned short ushort_t;
typedef short bf16x8 __attribute__((ext_vector_type(8)));
typedef float f32x4  __attribute__((ext_vector_type(4)));

__device__ __forceinline__ float bf2f(ushort_t u) {
    return __uint_as_float(((unsigned int)u) << 16);
}
__device__ __forceinline__ ushort_t f2bf(float f) {
    union { __hip_bfloat16 h; ushort_t u; } cv;
    cv.h = __float2bfloat16(f);
    return cv.u;
}

// async global->LDS, 16B per lane; LDS dest = wave-uniform base + lane*16
__device__ __forceinline__ void gload16(const void* g, void* l) {
    __builtin_amdgcn_global_load_lds(
        (const __attribute__((address_space(1))) unsigned int*)g,
        (__attribute__((address_space(3))) unsigned int*)l, 16, 0, 0);
}

// ---------------------------------------------------------------------------
// fp32 -> bf16 cast, 4 elems/thread
// ---------------------------------------------------------------------------
__global__ __launch_bounds__(256) void cast_f32_bf16(
    const float* __restrict__ x, ushort_t* __restrict__ y, int n4)
{
    const int i = blockIdx.x * 256 + threadIdx.x;
    if (i < n4) {
        const float4 v = ((const float4*)x)[i];
        ushort4 o;
        o.x = f2bf(v.x); o.y = f2bf(v.y); o.z = f2bf(v.z); o.w = f2bf(v.w);
        ((ushort4*)y)[i] = o;
    }
}

// ---------------------------------------------------------------------------
// bf16 MFMA GEMM (m97 pattern): Y[M,N] = A[M,K] @ W[N,K]^T + bias
// 128x128 tile, BK=32, 256 threads = 4 waves (2x2 of 64x64), 16x16x32 MFMA.
// BIAS_ROW=false: bias indexed by output col (normal Linear).
// BIAS_ROW=true:  bias indexed by output row (used for Vt = Wv @ value^T).
// ---------------------------------------------------------------------------
template <bool OUT_BF16, bool BIAS_ROW>
__global__ __launch_bounds__(256) void gemm_bt_mfma(
    const ushort_t* __restrict__ A,   // [M,K] bf16
    const ushort_t* __restrict__ W,   // [N,K] bf16
    const float*    __restrict__ bias,
    void* __restrict__ Yv,            // [M,N] bf16 or fp32
    int M, int N, int K)
{
    __shared__ ushort_t As[8 * 512];  // 8 slabs x 1024B
    __shared__ ushort_t Bs[8 * 512];

    const int tid  = threadIdx.x;
    const int lane = tid & 63;
    const int wave = tid >> 6;
    const int wm   = wave & 1;
    const int wn   = wave >> 1;
    const int m0   = blockIdx.y * 128;
    const int n0   = blockIdx.x * 128;
    const int lr   = lane & 15;
    const int lk   = (lane >> 4) * 8;

    const ushort_t* aP = A + (size_t)(m0 + wave * 32 + lr) * K + lk;
    const ushort_t* wP = W + (size_t)(n0 + wave * 32 + lr) * K + lk;
    ushort_t* aL = &As[wave * 1024];
    ushort_t* bL = &Bs[wave * 1024];

    f32x4 acc[4][4];
#pragma unroll
    for (int i = 0; i < 4; i++)
#pragma unroll
        for (int j = 0; j < 4; j++) acc[i][j] = (f32x4){0.f, 0.f, 0.f, 0.f};

    for (int k0 = 0; k0 < K; k0 += 32) {
        gload16(aP,          aL);
        gload16(aP + 16 * K, aL + 512);
        gload16(wP,          bL);
        gload16(wP + 16 * K, bL + 512);
        aP += 32; wP += 32;
        __syncthreads();

        bf16x8 af[4], bf[4];
#pragma unroll
        for (int i = 0; i < 4; i++)
            af[i] = *(const bf16x8*)&As[(wm * 4 + i) * 512 + lane * 8];
#pragma unroll
        for (int j = 0; j < 4; j++)
            bf[j] = *(const bf16x8*)&Bs[(wn * 4 + j) * 512 + lane * 8];
#pragma unroll
        for (int i = 0; i < 4; i++)
#pragma unroll
            for (int j = 0; j < 4; j++)
                acc[i][j] = __builtin_amdgcn_mfma_f32_16x16x32_bf16(
                    af[i], bf[j], acc[i][j], 0, 0, 0);
        __syncthreads();
    }

    // epilogue; C/D layout: col = lane&15, row = (lane>>4)*4 + reg
    const int orow = (lane >> 4) * 4;
    const int ocol = lane & 15;

#pragma unroll
    for (int i = 0; i < 4; i++) {
#pragma unroll
        for (int j = 0; j < 4; j++) {
            const int col = n0 + wn * 64 + j * 16 + ocol;
#pragma unroll
            for (int r = 0; r < 4; r++) {
                const int row = m0 + wm * 64 + i * 16 + orow + r;
                const float bvv = BIAS_ROW ? bias[row] : bias[col];
                const float v = acc[i][j][r] + bvv;
                if (OUT_BF16)
                    ((ushort_t*)Yv)[(size_t)row * N + col] = f2bf(v);
                else
                    ((float*)Yv)[(size_t)row * N + col] = v;
            }
        }
    }
}

// ---------------------------------------------------------------------------
// MFMA flash attention, zero barriers, paired q-tiles, XCD-local K/V,
// K-fragment register double-buffer — SWAPPED-OPERAND edition.
//
//  QK^T computed as mfma(K, Q) -> S^T (col = q = lane&15, row = key).
//  Each lane owns 16 scores of ONE q-row: row-max = 15 fmax + 2 shfls,
//  m/l/alpha are per-lane scalars, P^T stored with 4 packed ds_write_b64,
//  PV computed as mfma(V, P) -> O^T, epilogue packs ushort4.
//
//  ROUND-2 FIX: __launch_bounds__(256, 2) — round 1's (256,4) capped VGPRs
//  at 128 < ~170 live set, collapsing the allocator to 64 VGPRs with
//  catastrophic scratch spills (1.08 GB FETCH / 1.62 GB WRITE of pure
//  spill traffic, 57% HBM, 607 us). Cap 256 lets the live set sit in
//  registers (~150-190 expected, 2-3 waves/SIMD).
// ---------------------------------------------------------------------------
__global__ __launch_bounds__(256, 2) void attn_mfma(
    const ushort_t* __restrict__ Qp,   // [B*S, H]
    const ushort_t* __restrict__ Kp,   // [B*S, H]
    const ushort_t* __restrict__ Vt,   // [H, B*S]
    const float*    __restrict__ mask, // [B, S] over key positions
    ushort_t* __restrict__ Op)         // [B*S, H]
{
    __shared__ ushort_t Pl[4][16 * 72];  // per-wave P^T: [q=16][key=64], stride 72

    const int tid  = threadIdx.x;
    const int lane = tid & 63;
    const int wave = tid >> 6;
    const int li   = lane & 15;   // frag idx | C/D col (= q index)
    const int lq   = lane >> 4;   // quad
    const int blk  = blockIdx.x;
    // XCD-aware mapping: xcd = blk&7 (round-robin dispatch), 8 heads per XCD,
    // 16 blocks (pp=0..15) per (b,h), 4 pair-indices per block (one per wave).
    const int xcd = blk & 7;
    const int jj  = blk >> 3;            // 0..127
    const int bh  = xcd * 8 + (jj & 7);  // 0..63
    const int pp  = jj >> 3;             // 0..15
    const int pr  = pp * 4 + wave;       // 0..63: q-tiles {pr, 127-pr}
    const int h   = bh & (NH - 1);
    const int b   = bh >> 4;
    const int prow = lq * 4;      // this lane's C/D row base (= key/d offset)

    const ushort_t* kbase = Kp + ((size_t)b * SEQ + li) * HID + (size_t)h * DH + lq * 8;
    const ushort_t* vbase = Vt + ((size_t)h * DH + li) * MTOT + (size_t)b * SEQ + lq * 8;
    const float*    mbase = mask + (size_t)b * SEQ + prow;   // indexed by key+r
    ushort_t* pw = &Pl[wave][0];

#pragma unroll
    for (int t = 0; t < 2; t++) {
        const int qt = (t == 0) ? pr : (127 - pr);
        const int q0 = qt * 16;
        const int qrow = q0 + li;            // this lane's q position

        // persistent Q B-fragments (k-chunks 0,1 of dh=64)
        const size_t qaddr = ((size_t)b * SEQ + qrow) * HID + (size_t)h * DH + lq * 8;
        const bf16x8 qf0 = *(const bf16x8*)&Qp[qaddr];
        const bf16x8 qf1 = *(const bf16x8*)&Qp[qaddr + 32];

        f32x4 oa[4];                          // O^T: oa[nt][r] = O[q=li][d=nt*16+prow+r]
#pragma unroll
        for (int nt = 0; nt < 4; nt++) oa[nt] = (f32x4){0.f, 0.f, 0.f, 0.f};
        float m_i = -1e30f, l_i = 0.f;        // per-lane scalars (one q-row each)

        const int jmax = q0 >> 6;

        // ---- preload K A-frags for j=0 ----
        bf16x8 kf[4][2];
#pragma unroll
        for (int nt = 0; nt < 4; nt++) {
            const ushort_t* kp = kbase + (size_t)(nt * 16) * HID;
            kf[nt][0] = *(const bf16x8*)kp;
            kf[nt][1] = *(const bf16x8*)(kp + 32);
        }

        for (int j = 0; j <= jmax; j++) {
            const int k0 = j * 64;

            // ---- prefetch K frags for j+1 (consumed next iter) ----
            bf16x8 kn[4][2];
            if (j < jmax) {
                const int k1 = k0 + 64;
#pragma unroll
                for (int nt = 0; nt < 4; nt++) {
                    const ushort_t* kp = kbase + (size_t)(k1 + nt * 16) * HID;
                    kn[nt][0] = *(const bf16x8*)kp;
                    kn[nt][1] = *(const bf16x8*)(kp + 32);
                }
            }

            // ---- mask for current block (8KB/batch, L1/L2-resident; load
            //      latency hides under the QK MFMAs) ----
            f32x4 mk[4];
#pragma unroll
            for (int nt = 0; nt < 4; nt++)
                mk[nt] = *(const f32x4*)&mbase[k0 + nt * 16];

            // ---- hoist V A-frag loads: latency overlaps softmax below ----
            bf16x8 vf[4][2];
#pragma unroll
            for (int nt = 0; nt < 4; nt++) {
                const ushort_t* vp = vbase + (size_t)(nt * 16) * MTOT + k0;
                vf[nt][0] = *(const bf16x8*)vp;
                vf[nt][1] = *(const bf16x8*)(vp + 32);
            }

            // ---- S^T = K Q^T (per 16-key tile nt); col=q, row=key ----
            f32x4 sa[4];
            __builtin_amdgcn_s_setprio(1);
#pragma unroll
            for (int nt = 0; nt < 4; nt++) {
                f32x4 acc = (f32x4){0.f, 0.f, 0.f, 0.f};
                acc = __builtin_amdgcn_mfma_f32_16x16x32_bf16(kf[nt][0], qf0, acc, 0, 0, 0);
                acc = __builtin_amdgcn_mfma_f32_16x16x32_bf16(kf[nt][1], qf1, acc, 0, 0, 0);
                sa[nt] = acc;
            }
            __builtin_amdgcn_s_setprio(0);

            // ---- scale + padding mask + causal mask (all branchless) ----
            float s[4][4];
#pragma unroll
            for (int nt = 0; nt < 4; nt++)
#pragma unroll
                for (int r = 0; r < 4; r++) {
                    float v = sa[nt][r] * 0.125f;
                    s[nt][r] = (mk[nt][r] == 0.f) ? FILLV : v;
                }

            if (k0 + 63 > q0) {  // wave-uniform: diagonal-straddling tiles only
#pragma unroll
                for (int nt = 0; nt < 4; nt++) {
#pragma unroll
                    for (int r = 0; r < 4; r++) {
                        const int kpos = k0 + nt * 16 + prow + r;
                        s[nt][r] = (kpos > qrow) ? FILLV : s[nt][r];
                    }
                }
            }

            // ---- online softmax: lane-local row, 15 fmax + 2 shfls ----
            float pm = fmaxf(fmaxf(s[0][0], s[0][1]), fmaxf(s[0][2], s[0][3]));
#pragma unroll
            for (int nt = 1; nt < 4; nt++)
                pm = fmaxf(pm, fmaxf(fmaxf(s[nt][0], s[nt][1]),
                                     fmaxf(s[nt][2], s[nt][3])));
            pm = fmaxf(pm, __shfl_xor(pm, 16));
            pm = fmaxf(pm, __shfl_xor(pm, 32));
            const float mnew  = fmaxf(m_i, pm);
            const float alpha = __expf(m_i - mnew);
            m_i = mnew;

            float psum = 0.f;
#pragma unroll
            for (int nt = 0; nt < 4; nt++) {
                const float p0 = __expf(s[nt][0] - mnew);
                const float p1 = __expf(s[nt][1] - mnew);
                const float p2 = __expf(s[nt][2] - mnew);
                const float p3 = __expf(s[nt][3] - mnew);
                psum += (p0 + p1) + (p2 + p3);
                ushort4 pk;
                pk.x = f2bf(p0); pk.y = f2bf(p1); pk.z = f2bf(p2); pk.w = f2bf(p3);
                // P^T slab: [q=li][key = nt*16 + prow + 0..3], packed 8B write
                *(ushort4*)&pw[li * 72 + nt * 16 + prow] = pk;
            }
            psum += __shfl_xor(psum, 16);
            psum += __shfl_xor(psum, 32);
            l_i = l_i * alpha + psum;

            // ---- rescale O^T by scalar alpha (fills LDS-write latency) ----
#pragma unroll
            for (int nt = 0; nt < 4; nt++)
#pragma unroll
                for (int r = 0; r < 4; r++) oa[nt][r] *= alpha;

            // ---- P as B-fragments (same-wave LDS RAW -> compiler lgkmcnt) ----
            const bf16x8 pf0 = *(const bf16x8*)&pw[li * 72 + lq * 8];
            const bf16x8 pf1 = *(const bf16x8*)&pw[li * 72 + 32 + lq * 8];

            // ---- O^T += V^T P^T : mfma(V, P), col=q, row=d ----
            __builtin_amdgcn_s_setprio(1);
#pragma unroll
            for (int nt = 0; nt < 4; nt++) {
                f32x4 o = oa[nt];
                o = __builtin_amdgcn_mfma_f32_16x16x32_bf16(vf[nt][0], pf0, o, 0, 0, 0);
                o = __builtin_amdgcn_mfma_f32_16x16x32_bf16(vf[nt][1], pf1, o, 0, 0, 0);
                oa[nt] = o;
            }
            __builtin_amdgcn_s_setprio(0);

            // ---- rotate K double-buffer ----
            if (j < jmax) {
#pragma unroll
                for (int nt = 0; nt < 4; nt++) {
                    kf[nt][0] = kn[nt][0];
                    kf[nt][1] = kn[nt][1];
                }
            }
        }

        // ---- normalize + packed bf16 store (4x 8B per tile) ----
        const float linv = 1.f / l_i;
        const size_t obase = ((size_t)b * SEQ + qrow) * HID + (size_t)h * DH + prow;
#pragma unroll
        for (int nt = 0; nt < 4; nt++) {
            ushort4 ov;
            ov.x = f2bf(oa[nt][0] * linv);
            ov.y = f2bf(oa[nt][1] * linv);
            ov.z = f2bf(oa[nt][2] * linv);
            ov.w = f2bf(oa[nt][3] * linv);
            *(ushort4*)&Op[obase + nt * 16] = ov;
        }
    }
}

// ---------------------------------------------------------------------------
extern "C" void kernel_launch(void* const* d_in, const int* in_sizes, int n_in,
                              void* d_out, int out_size, void* d_ws, size_t ws_size,
                              hipStream_t stream) {
    const float* query = (const float*)d_in[0];
    const float* key   = (const float*)d_in[1];
    const float* value = (const float*)d_in[2];
    const float* mask  = (const float*)d_in[3];
    const float* Wq    = (const float*)d_in[4];
    const float* bq    = (const float*)d_in[5];
    const float* Wk    = (const float*)d_in[6];
    const float* bk    = (const float*)d_in[7];
    const float* Wv    = (const float*)d_in[8];
    const float* bv    = (const float*)d_in[9];
    const float* Wo    = (const float*)d_in[10];
    const float* bo    = (const float*)d_in[11];

    // workspace (bf16): 7 activation-size buffers + 4 weight buffers ≈ 125.5 MB
    const size_t eA = (size_t)MTOT * HID;
    const size_t eW = (size_t)HID * HID;
    ushort_t* qb  = (ushort_t*)d_ws;
    ushort_t* kb  = qb  + eA;
    ushort_t* vb  = kb  + eA;
    ushort_t* Qp  = vb  + eA;
    ushort_t* Kp  = Qp  + eA;
    ushort_t* Vtb = Kp  + eA;   // [H, B*S]
    ushort_t* Op  = Vtb + eA;
    ushort_t* wqb = Op  + eA;
    ushort_t* wkb = wqb + eW;
    ushort_t* wvb = wkb + eW;
    ushort_t* wob = wvb + eW;

    const int n4a = (int)(eA / 4), n4w = (int)(eW / 4);
    cast_f32_bf16<<<(n4a + 255) / 256, 256, 0, stream>>>(query, qb, n4a);
    cast_f32_bf16<<<(n4a + 255) / 256, 256, 0, stream>>>(key,   kb, n4a);
    cast_f32_bf16<<<(n4a + 255) / 256, 256, 0, stream>>>(value, vb, n4a);
    cast_f32_bf16<<<(n4w + 255) / 256, 256, 0, stream>>>(Wq, wqb, n4w);
    cast_f32_bf16<<<(n4w + 255) / 256, 256, 0, stream>>>(Wk, wkb, n4w);
    cast_f32_bf16<<<(n4w + 255) / 256, 256, 0, stream>>>(Wv, wvb, n4w);
    cast_f32_bf16<<<(n4w + 255) / 256, 256, 0, stream>>>(Wo, wob, n4w);

    dim3 gg(HID / 128, MTOT / 128);   // (8, 64)
    gemm_bt_mfma<true, false><<<gg, 256, 0, stream>>>(qb, wqb, bq, Qp, MTOT, HID, HID);
    gemm_bt_mfma<true, false><<<gg, 256, 0, stream>>>(kb, wkb, bk, Kp, MTOT, HID, HID);
    // Vt = Wv @ value^T  -> [H, B*S], bias by row (bv[d])
    dim3 gv(MTOT / 128, HID / 128);   // (64, 8)
    gemm_bt_mfma<true, true><<<gv, 256, 0, stream>>>(wvb, vb, bv, Vtb, HID, MTOT, HID);

    // flash attention: 4096 uniform waves, XCD-local (b,h), 4 waves/block
    attn_mfma<<<(BATCH * NH * 64) / 4, 256, 0, stream>>>(Qp, Kp, Vtb, mask, Op);

    gemm_bt_mfma<false, false><<<gg, 256, 0, stream>>>(Op, wob, bo, d_out, MTOT, HID, HID);
}

// Round 3
// 420.373 us; speedup vs baseline: 2.2110x; 1.3696x over previous
//
#include <hip/hip_runtime.h>
#include <hip/hip_bf16.h>
#include <math.h>

// Problem constants: B=4, S=2048, H=1024, nh=16, dh=64.
#define BATCH 4
#define SEQ   2048
#define HID   1024
#define NH    16
#define DH    64
#define MTOT  (BATCH * SEQ)   // 8192
#define FILLV (-1e13f)

typedef unsigned short ushort_t;
typedef short bf16x8 __attribute__((ext_vector_type(8)));
typedef float f32x4  __attribute__((ext_vector_type(4)));

__device__ __forceinline__ float bf2f(ushort_t u) {
    return __uint_as_float(((unsigned int)u) << 16);
}
__device__ __forceinline__ ushort_t f2bf(float f) {
    union { __hip_bfloat16 h; ushort_t u; } cv;
    cv.h = __float2bfloat16(f);
    return cv.u;
}

// async global->LDS, 16B per lane; LDS dest = wave-uniform base + lane*16
__device__ __forceinline__ void gload16(const void* g, void* l) {
    __builtin_amdgcn_global_load_lds(
        (const __attribute__((address_space(1))) unsigned int*)g,
        (__attribute__((address_space(3))) unsigned int*)l, 16, 0, 0);
}

// ---------------------------------------------------------------------------
// fp32 -> bf16 cast, 4 elems/thread
// ---------------------------------------------------------------------------
__global__ __launch_bounds__(256) void cast_f32_bf16(
    const float* __restrict__ x, ushort_t* __restrict__ y, int n4)
{
    const int i = blockIdx.x * 256 + threadIdx.x;
    if (i < n4) {
        const float4 v = ((const float4*)x)[i];
        ushort4 o;
        o.x = f2bf(v.x); o.y = f2bf(v.y); o.z = f2bf(v.z); o.w = f2bf(v.w);
        ((ushort4*)y)[i] = o;
    }
}

// ---------------------------------------------------------------------------
// bf16 MFMA GEMM (m97 pattern): Y[M,N] = A[M,K] @ W[N,K]^T + bias
// ---------------------------------------------------------------------------
template <bool OUT_BF16, bool BIAS_ROW>
__global__ __launch_bounds__(256) void gemm_bt_mfma(
    const ushort_t* __restrict__ A,   // [M,K] bf16
    const ushort_t* __restrict__ W,   // [N,K] bf16
    const float*    __restrict__ bias,
    void* __restrict__ Yv,            // [M,N] bf16 or fp32
    int M, int N, int K)
{
    __shared__ ushort_t As[8 * 512];  // 8 slabs x 1024B
    __shared__ ushort_t Bs[8 * 512];

    const int tid  = threadIdx.x;
    const int lane = tid & 63;
    const int wave = tid >> 6;
    const int wm   = wave & 1;
    const int wn   = wave >> 1;
    const int m0   = blockIdx.y * 128;
    const int n0   = blockIdx.x * 128;
    const int lr   = lane & 15;
    const int lk   = (lane >> 4) * 8;

    const ushort_t* aP = A + (size_t)(m0 + wave * 32 + lr) * K + lk;
    const ushort_t* wP = W + (size_t)(n0 + wave * 32 + lr) * K + lk;
    ushort_t* aL = &As[wave * 1024];
    ushort_t* bL = &Bs[wave * 1024];

    f32x4 acc[4][4];
#pragma unroll
    for (int i = 0; i < 4; i++)
#pragma unroll
        for (int j = 0; j < 4; j++) acc[i][j] = (f32x4){0.f, 0.f, 0.f, 0.f};

    for (int k0 = 0; k0 < K; k0 += 32) {
        gload16(aP,          aL);
        gload16(aP + 16 * K, aL + 512);
        gload16(wP,          bL);
        gload16(wP + 16 * K, bL + 512);
        aP += 32; wP += 32;
        __syncthreads();

        bf16x8 af[4], bf[4];
#pragma unroll
        for (int i = 0; i < 4; i++)
            af[i] = *(const bf16x8*)&As[(wm * 4 + i) * 512 + lane * 8];
#pragma unroll
        for (int j = 0; j < 4; j++)
            bf[j] = *(const bf16x8*)&Bs[(wn * 4 + j) * 512 + lane * 8];
#pragma unroll
        for (int i = 0; i < 4; i++)
#pragma unroll
            for (int j = 0; j < 4; j++)
                acc[i][j] = __builtin_amdgcn_mfma_f32_16x16x32_bf16(
                    af[i], bf[j], acc[i][j], 0, 0, 0);
        __syncthreads();
    }

    // epilogue; C/D layout: col = lane&15, row = (lane>>4)*4 + reg
    const int orow = (lane >> 4) * 4;
    const int ocol = lane & 15;

#pragma unroll
    for (int i = 0; i < 4; i++) {
#pragma unroll
        for (int j = 0; j < 4; j++) {
            const int col = n0 + wn * 64 + j * 16 + ocol;
#pragma unroll
            for (int r = 0; r < 4; r++) {
                const int row = m0 + wm * 64 + i * 16 + orow + r;
                const float bvv = BIAS_ROW ? bias[row] : bias[col];
                const float v = acc[i][j][r] + bvv;
                if (OUT_BF16)
                    ((ushort_t*)Yv)[(size_t)row * N + col] = f2bf(v);
                else
                    ((float*)Yv)[(size_t)row * N + col] = v;
            }
        }
    }
}

// ---------------------------------------------------------------------------
// MFMA flash attention v3: block-cooperative LDS-staged K/V, swapped-operand
// softmax, merged dual q-tiles.
//
//  Key facts exploited:
//   * All 4 waves in a block share (b,h) AND identical j-ranges:
//     pr = pp*4+wave (wave<4) -> jmaxA = pr>>2 = pp, jmaxB = 31-pp for every
//     wave. So K/V tiles can be staged cooperatively, in lockstep.
//   * Round-2 counters showed 20 VMEM loads/wave/iter with a 96-VGPR load
//     buffer the allocator (104 VGPRs) could not keep live -> compiler
//     serialized the "prefetch", exposing L2 latency every iteration
//     (dur identical to round 0 despite -12pts VALUBusy).
//  Fix: double-buffered global_load_lds staging (no dest VGPRs), counted
//  s_waitcnt vmcnt(9) so the next tile's loads stay in flight a full
//  iteration (T4), raw s_barrier (no vmcnt(0) drain). K/V LDS XOR-swizzled
//  via pre-swizzled GLOBAL source (m173) so ds_read_b128 frags are 2-way
//  bank-aliased (free). Both q-tiles {pr, 127-pr} processed per staged tile
//  (tile A active while j<=pp) -> 2x MFMA per staged byte.
// ---------------------------------------------------------------------------
__global__ __launch_bounds__(256, 2) void attn_mfma(
    const ushort_t* __restrict__ Qp,   // [B*S, H]
    const ushort_t* __restrict__ Kp,   // [B*S, H]
    const ushort_t* __restrict__ Vt,   // [H, B*S]
    const float*    __restrict__ mask, // [B, S] over key positions
    ushort_t* __restrict__ Op)         // [B*S, H]
{
    __shared__ ushort_t Kl[2][4096];     // [buf][64 rows x 64 elem] 8KB each
    __shared__ ushort_t Vl[2][4096];
    __shared__ ushort_t PlA[4][16 * 72]; // per-wave P^T slabs
    __shared__ ushort_t PlB[4][16 * 72];

    const int tid  = threadIdx.x;
    const int lane = tid & 63;
    const int wave = tid >> 6;
    const int li   = lane & 15;   // frag idx | C/D col (= q index)
    const int lq   = lane >> 4;   // quad
    const int blk  = blockIdx.x;
    // XCD-aware mapping: xcd = blk&7, 8 heads per XCD, 16 blocks per (b,h).
    const int xcd = blk & 7;
    const int jj  = blk >> 3;            // 0..127
    const int bh  = xcd * 8 + (jj & 7);  // 0..63
    const int pp  = jj >> 3;             // 0..15
    const int pr  = pp * 4 + wave;       // 0..63
    const int h   = bh & (NH - 1);
    const int b   = bh >> 4;
    const int prow = lq * 4;

    const int q0a = pr * 16;             // tile A (jmaxA = pp)
    const int q0b = (127 - pr) * 16;     // tile B (jmaxB = 31-pp)
    const int qrowA = q0a + li;
    const int qrowB = q0b + li;
    const int jmaxB = 31 - pp;

    const size_t bSEQ = (size_t)b * SEQ;
    const int    hoff = h * DH;

    // staging coords: row = tid>>3 (0..31, +32 on 2nd issue), chunk = tid&7,
    // source chunk pre-swizzled so LDS-linear dest == XOR-swizzled layout
    const int srow = tid >> 3;
    const int scs8 = ((tid & 7) ^ (srow & 7)) * 8;   // swizzled chunk * 8 elems

    // frag read offset (elements): row li (+nt*16), chunk0 = lq ^ (li&7)
    const int fr0 = li * 64 + ((lq ^ (li & 7)) * 8);

    ushort_t* pwA = &PlA[wave][0];
    ushort_t* pwB = &PlB[wave][0];

    const float* mbase = mask + bSEQ + prow;   // padding mask, indexed by key

    // persistent Q B-fragments
    const size_t qaA = (bSEQ + qrowA) * HID + hoff + lq * 8;
    const size_t qaB = (bSEQ + qrowB) * HID + hoff + lq * 8;
    const bf16x8 qfA0 = *(const bf16x8*)&Qp[qaA];
    const bf16x8 qfA1 = *(const bf16x8*)&Qp[qaA + 32];
    const bf16x8 qfB0 = *(const bf16x8*)&Qp[qaB];
    const bf16x8 qfB1 = *(const bf16x8*)&Qp[qaB + 32];

    f32x4 oaA[4], oaB[4];
#pragma unroll
    for (int nt = 0; nt < 4; nt++) {
        oaA[nt] = (f32x4){0.f, 0.f, 0.f, 0.f};
        oaB[nt] = (f32x4){0.f, 0.f, 0.f, 0.f};
    }
    float mA = -1e30f, lA = 0.f, mB = -1e30f, lB = 0.f;

    // stage tile js (keys js*64..+63) into buffer bs: 5 VMEM per thread
    auto STAGE = [&](int js, int bs) {
        const size_t k0s = (size_t)js * 64;
        const ushort_t* kg = Kp + (bSEQ + k0s + srow) * HID + hoff + scs8;
        ushort_t* kl = &Kl[bs][wave * 512];
        gload16(kg, kl);
        gload16(kg + (size_t)32 * HID, kl + 2048);
        const ushort_t* vg = Vt + (size_t)(hoff + srow) * MTOT + bSEQ + k0s + scs8;
        ushort_t* vl = &Vl[bs][wave * 512];
        gload16(vg, vl);
        gload16(vg + (size_t)32 * MTOT, vl + 2048);
    };

    STAGE(0, 0);   // prologue: 4 VMEM outstanding (+4 qf loads)

    for (int j = 0; j <= jmaxB; ++j) {
        const int  k0  = j * 64;
        const int  bs  = j & 1;
        const bool doA = (j <= pp);          // block-uniform

        // ---- padding mask, plain per-lane loads (pinned before STAGE) ----
        f32x4 mk[4];
#pragma unroll
        for (int nt = 0; nt < 4; nt++)
            mk[nt] = *(const f32x4*)&mbase[k0 + nt * 16];
        __builtin_amdgcn_sched_barrier(0);

        // ---- prefetch next tile (never drained this iteration: T4) ----
        const int jn = (j < jmaxB) ? (j + 1) : jmaxB;
        STAGE(jn, bs ^ 1);

        // outstanding: stage(j)=4 (oldest) + mask=4 + stage(j+1)=4 -> wait
        // until <=8 completes exactly stage(j); stage(j+1)+mask stay in flight
        asm volatile("s_waitcnt vmcnt(8)" ::: "memory");
        __builtin_amdgcn_s_barrier();
        __builtin_amdgcn_sched_barrier(0);

        // ---- K fragments from LDS (swizzled) ----
        bf16x8 kf[4][2];
#pragma unroll
        for (int nt = 0; nt < 4; nt++) {
            const int eo = nt * 1024 + fr0;
            kf[nt][0] = *(const bf16x8*)&Kl[bs][eo];
            kf[nt][1] = *(const bf16x8*)&Kl[bs][eo ^ 32];
        }

        // ---- S^T = K Q^T for both q-tiles ----
        f32x4 saA[4], saB[4];
        __builtin_amdgcn_s_setprio(1);
#pragma unroll
        for (int nt = 0; nt < 4; nt++) {
            f32x4 a = (f32x4){0.f, 0.f, 0.f, 0.f};
            a = __builtin_amdgcn_mfma_f32_16x16x32_bf16(kf[nt][0], qfB0, a, 0, 0, 0);
            a = __builtin_amdgcn_mfma_f32_16x16x32_bf16(kf[nt][1], qfB1, a, 0, 0, 0);
            saB[nt] = a;
        }
        if (doA) {
#pragma unroll
            for (int nt = 0; nt < 4; nt++) {
                f32x4 a = (f32x4){0.f, 0.f, 0.f, 0.f};
                a = __builtin_amdgcn_mfma_f32_16x16x32_bf16(kf[nt][0], qfA0, a, 0, 0, 0);
                a = __builtin_amdgcn_mfma_f32_16x16x32_bf16(kf[nt][1], qfA1, a, 0, 0, 0);
                saA[nt] = a;
            }
        }
        __builtin_amdgcn_s_setprio(0);

        // ---- tile B: scale + mask + online softmax (lane-local row) ----
        float sB[4][4];
#pragma unroll
        for (int nt = 0; nt < 4; nt++)
#pragma unroll
            for (int r = 0; r < 4; r++) {
                const float v = saB[nt][r] * 0.125f;
                sB[nt][r] = (mk[nt][r] == 0.f) ? FILLV : v;
            }
        if (k0 + 63 > q0b) {
#pragma unroll
            for (int nt = 0; nt < 4; nt++)
#pragma unroll
                for (int r = 0; r < 4; r++) {
                    const int kpos = k0 + nt * 16 + prow + r;
                    sB[nt][r] = (kpos > qrowB) ? FILLV : sB[nt][r];
                }
        }
        float pmB = fmaxf(fmaxf(sB[0][0], sB[0][1]), fmaxf(sB[0][2], sB[0][3]));
#pragma unroll
        for (int nt = 1; nt < 4; nt++)
            pmB = fmaxf(pmB, fmaxf(fmaxf(sB[nt][0], sB[nt][1]),
                                   fmaxf(sB[nt][2], sB[nt][3])));
        pmB = fmaxf(pmB, __shfl_xor(pmB, 16));
        pmB = fmaxf(pmB, __shfl_xor(pmB, 32));
        const float mnB = fmaxf(mB, pmB);
        const float alB = __expf(mB - mnB);
        mB = mnB;
        float psB = 0.f;
#pragma unroll
        for (int nt = 0; nt < 4; nt++) {
            const float p0 = __expf(sB[nt][0] - mnB);
            const float p1 = __expf(sB[nt][1] - mnB);
            const float p2 = __expf(sB[nt][2] - mnB);
            const float p3 = __expf(sB[nt][3] - mnB);
            psB += (p0 + p1) + (p2 + p3);
            ushort4 pk;
            pk.x = f2bf(p0); pk.y = f2bf(p1); pk.z = f2bf(p2); pk.w = f2bf(p3);
            *(ushort4*)&pwB[li * 72 + nt * 16 + prow] = pk;
        }
        psB += __shfl_xor(psB, 16);
        psB += __shfl_xor(psB, 32);
        lB = lB * alB + psB;

        // ---- tile A softmax (only while active) ----
        float alA = 1.f;
        if (doA) {
            float sA[4][4];
#pragma unroll
            for (int nt = 0; nt < 4; nt++)
#pragma unroll
                for (int r = 0; r < 4; r++) {
                    const float v = saA[nt][r] * 0.125f;
                    sA[nt][r] = (mk[nt][r] == 0.f) ? FILLV : v;
                }
            if (k0 + 63 > q0a) {
#pragma unroll
                for (int nt = 0; nt < 4; nt++)
#pragma unroll
                    for (int r = 0; r < 4; r++) {
                        const int kpos = k0 + nt * 16 + prow + r;
                        sA[nt][r] = (kpos > qrowA) ? FILLV : sA[nt][r];
                    }
            }
            float pmA = fmaxf(fmaxf(sA[0][0], sA[0][1]), fmaxf(sA[0][2], sA[0][3]));
#pragma unroll
            for (int nt = 1; nt < 4; nt++)
                pmA = fmaxf(pmA, fmaxf(fmaxf(sA[nt][0], sA[nt][1]),
                                       fmaxf(sA[nt][2], sA[nt][3])));
            pmA = fmaxf(pmA, __shfl_xor(pmA, 16));
            pmA = fmaxf(pmA, __shfl_xor(pmA, 32));
            const float mnA = fmaxf(mA, pmA);
            alA = __expf(mA - mnA);
            mA = mnA;
            float psA = 0.f;
#pragma unroll
            for (int nt = 0; nt < 4; nt++) {
                const float p0 = __expf(sA[nt][0] - mnA);
                const float p1 = __expf(sA[nt][1] - mnA);
                const float p2 = __expf(sA[nt][2] - mnA);
                const float p3 = __expf(sA[nt][3] - mnA);
                psA += (p0 + p1) + (p2 + p3);
                ushort4 pk;
                pk.x = f2bf(p0); pk.y = f2bf(p1); pk.z = f2bf(p2); pk.w = f2bf(p3);
                *(ushort4*)&pwA[li * 72 + nt * 16 + prow] = pk;
            }
            psA += __shfl_xor(psA, 16);
            psA += __shfl_xor(psA, 32);
            lA = lA * alA + psA;
        }

        // ---- V fragments + P fragments ----
        const bf16x8 pfB0 = *(const bf16x8*)&pwB[li * 72 + lq * 8];
        const bf16x8 pfB1 = *(const bf16x8*)&pwB[li * 72 + 32 + lq * 8];
        bf16x8 vf[4][2];
#pragma unroll
        for (int nt = 0; nt < 4; nt++) {
            const int eo = nt * 1024 + fr0;
            vf[nt][0] = *(const bf16x8*)&Vl[bs][eo];
            vf[nt][1] = *(const bf16x8*)&Vl[bs][eo ^ 32];
        }

        // ---- O^T += V^T P^T ----
        __builtin_amdgcn_s_setprio(1);
#pragma unroll
        for (int nt = 0; nt < 4; nt++) {
            f32x4 o = oaB[nt];
#pragma unroll
            for (int r = 0; r < 4; r++) o[r] *= alB;
            o = __builtin_amdgcn_mfma_f32_16x16x32_bf16(vf[nt][0], pfB0, o, 0, 0, 0);
            o = __builtin_amdgcn_mfma_f32_16x16x32_bf16(vf[nt][1], pfB1, o, 0, 0, 0);
            oaB[nt] = o;
        }
        __builtin_amdgcn_s_setprio(0);
        if (doA) {
            const bf16x8 pfA0 = *(const bf16x8*)&pwA[li * 72 + lq * 8];
            const bf16x8 pfA1 = *(const bf16x8*)&pwA[li * 72 + 32 + lq * 8];
            __builtin_amdgcn_s_setprio(1);
#pragma unroll
            for (int nt = 0; nt < 4; nt++) {
                f32x4 o = oaA[nt];
#pragma unroll
                for (int r = 0; r < 4; r++) o[r] *= alA;
                o = __builtin_amdgcn_mfma_f32_16x16x32_bf16(vf[nt][0], pfA0, o, 0, 0, 0);
                o = __builtin_amdgcn_mfma_f32_16x16x32_bf16(vf[nt][1], pfA1, o, 0, 0, 0);
                oaA[nt] = o;
            }
            __builtin_amdgcn_s_setprio(0);
        }

        // all waves done READING buf[bs] before next iter's STAGE overwrites it
        __builtin_amdgcn_sched_barrier(0);
        __builtin_amdgcn_s_barrier();
    }
    // drain the redundant last prefetch before s_endpgm (LDS writes in flight)
    asm volatile("s_waitcnt vmcnt(0)" ::: "memory");

    // ---- normalize + packed bf16 stores ----
    {
        const float linv = 1.f / lB;
        const size_t obase = (bSEQ + qrowB) * HID + hoff + prow;
#pragma unroll
        for (int nt = 0; nt < 4; nt++) {
            ushort4 ov;
            ov.x = f2bf(oaB[nt][0] * linv);
            ov.y = f2bf(oaB[nt][1] * linv);
            ov.z = f2bf(oaB[nt][2] * linv);
            ov.w = f2bf(oaB[nt][3] * linv);
            *(ushort4*)&Op[obase + nt * 16] = ov;
        }
    }
    {
        const float linv = 1.f / lA;
        const size_t obase = (bSEQ + qrowA) * HID + hoff + prow;
#pragma unroll
        for (int nt = 0; nt < 4; nt++) {
            ushort4 ov;
            ov.x = f2bf(oaA[nt][0] * linv);
            ov.y = f2bf(oaA[nt][1] * linv);
            ov.z = f2bf(oaA[nt][2] * linv);
            ov.w = f2bf(oaA[nt][3] * linv);
            *(ushort4*)&Op[obase + nt * 16] = ov;
        }
    }
}

// ---------------------------------------------------------------------------
extern "C" void kernel_launch(void* const* d_in, const int* in_sizes, int n_in,
                              void* d_out, int out_size, void* d_ws, size_t ws_size,
                              hipStream_t stream) {
    const float* query = (const float*)d_in[0];
    const float* key   = (const float*)d_in[1];
    const float* value = (const float*)d_in[2];
    const float* mask  = (const float*)d_in[3];
    const float* Wq    = (const float*)d_in[4];
    const float* bq    = (const float*)d_in[5];
    const float* Wk    = (const float*)d_in[6];
    const float* bk    = (const float*)d_in[7];
    const float* Wv    = (const float*)d_in[8];
    const float* bv    = (const float*)d_in[9];
    const float* Wo    = (const float*)d_in[10];
    const float* bo    = (const float*)d_in[11];

    // workspace (bf16): 7 activation-size buffers + 4 weight buffers ≈ 125.5 MB
    const size_t eA = (size_t)MTOT * HID;
    const size_t eW = (size_t)HID * HID;
    ushort_t* qb  = (ushort_t*)d_ws;
    ushort_t* kb  = qb  + eA;
    ushort_t* vb  = kb  + eA;
    ushort_t* Qp  = vb  + eA;
    ushort_t* Kp  = Qp  + eA;
    ushort_t* Vtb = Kp  + eA;   // [H, B*S]
    ushort_t* Op  = Vtb + eA;
    ushort_t* wqb = Op  + eA;
    ushort_t* wkb = wqb + eW;
    ushort_t* wvb = wkb + eW;
    ushort_t* wob = wvb + eW;

    const int n4a = (int)(eA / 4), n4w = (int)(eW / 4);
    cast_f32_bf16<<<(n4a + 255) / 256, 256, 0, stream>>>(query, qb, n4a);
    cast_f32_bf16<<<(n4a + 255) / 256, 256, 0, stream>>>(key,   kb, n4a);
    cast_f32_bf16<<<(n4a + 255) / 256, 256, 0, stream>>>(value, vb, n4a);
    cast_f32_bf16<<<(n4w + 255) / 256, 256, 0, stream>>>(Wq, wqb, n4w);
    cast_f32_bf16<<<(n4w + 255) / 256, 256, 0, stream>>>(Wk, wkb, n4w);
    cast_f32_bf16<<<(n4w + 255) / 256, 256, 0, stream>>>(Wv, wvb, n4w);
    cast_f32_bf16<<<(n4w + 255) / 256, 256, 0, stream>>>(Wo, wob, n4w);

    dim3 gg(HID / 128, MTOT / 128);   // (8, 64)
    gemm_bt_mfma<true, false><<<gg, 256, 0, stream>>>(qb, wqb, bq, Qp, MTOT, HID, HID);
    gemm_bt_mfma<true, false><<<gg, 256, 0, stream>>>(kb, wkb, bk, Kp, MTOT, HID, HID);
    // Vt = Wv @ value^T  -> [H, B*S], bias by row (bv[d])
    dim3 gv(MTOT / 128, HID / 128);   // (64, 8)
    gemm_bt_mfma<true, true><<<gv, 256, 0, stream>>>(wvb, vb, bv, Vtb, HID, MTOT, HID);

    // flash attention: 1024 blocks, 4 waves each, XCD-local (b,h)
    attn_mfma<<<(BATCH * NH * 64) / 4, 256, 0, stream>>>(Qp, Kp, Vtb, mask, Op);

    gemm_bt_mfma<false, false><<<gg, 256, 0, stream>>>(Op, wob, bo, d_out, MTOT, HID, HID);
}

// Round 4
// 411.895 us; speedup vs baseline: 2.2566x; 1.0206x over previous
//
#include <hip/hip_runtime.h>
#include <hip/hip_bf16.h>
#include <math.h>

// Problem constants: B=4, S=2048, H=1024, nh=16, dh=64.
#define BATCH 4
#define SEQ   2048
#define HID   1024
#define NH    16
#define DH    64
#define MTOT  (BATCH * SEQ)   // 8192
#define FILLV (-1e13f)

typedef unsigned short ushort_t;
typedef short bf16x8 __attribute__((ext_vector_type(8)));
typedef float f32x4  __attribute__((ext_vector_type(4)));

__device__ __forceinline__ float bf2f(ushort_t u) {
    return __uint_as_float(((unsigned int)u) << 16);
}
__device__ __forceinline__ ushort_t f2bf(float f) {
    union { __hip_bfloat16 h; ushort_t u; } cv;
    cv.h = __float2bfloat16(f);
    return cv.u;
}

// async global->LDS, 16B per lane; LDS dest = wave-uniform base + lane*16
__device__ __forceinline__ void gload16(const void* g, void* l) {
    __builtin_amdgcn_global_load_lds(
        (const __attribute__((address_space(1))) unsigned int*)g,
        (__attribute__((address_space(3))) unsigned int*)l, 16, 0, 0);
}

// ---------------------------------------------------------------------------
// fp32 -> bf16 cast, 4 elems/thread
// ---------------------------------------------------------------------------
__global__ __launch_bounds__(256) void cast_f32_bf16(
    const float* __restrict__ x, ushort_t* __restrict__ y, int n4)
{
    const int i = blockIdx.x * 256 + threadIdx.x;
    if (i < n4) {
        const float4 v = ((const float4*)x)[i];
        ushort4 o;
        o.x = f2bf(v.x); o.y = f2bf(v.y); o.z = f2bf(v.z); o.w = f2bf(v.w);
        ((ushort4*)y)[i] = o;
    }
}

// ---------------------------------------------------------------------------
// bf16 MFMA GEMM v2: Y[M,N] = A[M,K] @ W[N,K]^T + bias
// 128x128 tile, BK=32, 256 threads = 4 waves (2x2 of 64x64), 16x16x32 MFMA.
//
// ROUND-4: the m97-style loop drained vmcnt to 0 at every __syncthreads,
// exposing full staging latency 32x per block (only 2 blocks/CU at this
// shape -> no TLP to hide it; GEMMs ran at ~240 TF). Changes:
//  * double-buffered LDS + counted s_waitcnt vmcnt(4): next tile's 4
//    global_load_lds stay in flight across the whole compute phase (T3/T4,
//    same recipe that took attn 265->102 us).
//  * XCD-chunked bijective block swizzle (nwg=512): all 8 blocks sharing an
//    A-panel land on ONE XCD -> A-panel L2-hits; W (2MB) L2-resident.
// ---------------------------------------------------------------------------
template <bool OUT_BF16, bool BIAS_ROW>
__global__ __launch_bounds__(256) void gemm_bt_mfma(
    const ushort_t* __restrict__ A,   // [M,K] bf16
    const ushort_t* __restrict__ W,   // [N,K] bf16
    const float*    __restrict__ bias,
    void* __restrict__ Yv,            // [M,N] bf16 or fp32
    int M, int N, int K)
{
    __shared__ ushort_t As[2][4096];  // [buf][8 slabs x 512 elems]
    __shared__ ushort_t Bs[2][4096];

    const int tid  = threadIdx.x;
    const int lane = tid & 63;
    const int wave = tid >> 6;
    const int wm   = wave & 1;
    const int wn   = wave >> 1;

    // XCD-chunked swizzle: xcd = flat&7 (round-robin dispatch), give each XCD
    // a contiguous chunk of nwg/8 flat-ids. Bijective since nwg % 8 == 0.
    const int flat = blockIdx.y * gridDim.x + blockIdx.x;
    const int cpx  = (gridDim.x * gridDim.y) >> 3;
    const int fl2  = (flat & 7) * cpx + (flat >> 3);
    const int bx   = fl2 % gridDim.x;
    const int by   = fl2 / gridDim.x;

    const int m0   = by * 128;
    const int n0   = bx * 128;
    const int lr   = lane & 15;
    const int lk   = (lane >> 4) * 8;

    f32x4 acc[4][4];
#pragma unroll
    for (int i = 0; i < 4; i++)
#pragma unroll
        for (int j = 0; j < 4; j++) acc[i][j] = (f32x4){0.f, 0.f, 0.f, 0.f};

    // stage K-chunk starting at col kk into buffer d (4 VMEM per thread)
    auto STAGE = [&](int kk, int d) {
        const ushort_t* a = A + (size_t)(m0 + wave * 32 + lr) * K + kk + lk;
        const ushort_t* w = W + (size_t)(n0 + wave * 32 + lr) * K + kk + lk;
        ushort_t* al = &As[d][wave * 1024];
        ushort_t* bl = &Bs[d][wave * 1024];
        gload16(a,                 al);
        gload16(a + (size_t)16 * K, al + 512);
        gload16(w,                 bl);
        gload16(w + (size_t)16 * K, bl + 512);
    };

    const int nk = K >> 5;
    STAGE(0, 0);

    for (int kt = 0; kt < nk; ++kt) {
        const int d = kt & 1;
        if (kt + 1 < nk) {
            STAGE((kt + 1) << 5, d ^ 1);
            // outstanding: stage(kt)=4 oldest + stage(kt+1)=4 -> wait to <=4:
            // stage(kt) landed, stage(kt+1) stays in flight through compute.
            asm volatile("s_waitcnt vmcnt(4)" ::: "memory");
        } else {
            asm volatile("s_waitcnt vmcnt(0)" ::: "memory");
        }
        __builtin_amdgcn_s_barrier();
        __builtin_amdgcn_sched_barrier(0);

        bf16x8 af[4], bf[4];
#pragma unroll
        for (int i = 0; i < 4; i++)
            af[i] = *(const bf16x8*)&As[d][(wm * 4 + i) * 512 + lane * 8];
#pragma unroll
        for (int j = 0; j < 4; j++)
            bf[j] = *(const bf16x8*)&Bs[d][(wn * 4 + j) * 512 + lane * 8];
#pragma unroll
        for (int i = 0; i < 4; i++)
#pragma unroll
            for (int j = 0; j < 4; j++)
                acc[i][j] = __builtin_amdgcn_mfma_f32_16x16x32_bf16(
                    af[i], bf[j], acc[i][j], 0, 0, 0);

        // all waves done READING buf d before next iter's STAGE overwrites it
        __builtin_amdgcn_sched_barrier(0);
        __builtin_amdgcn_s_barrier();
    }

    // epilogue; C/D layout: col = lane&15, row = (lane>>4)*4 + reg
    const int orow = (lane >> 4) * 4;
    const int ocol = lane & 15;

#pragma unroll
    for (int i = 0; i < 4; i++) {
#pragma unroll
        for (int j = 0; j < 4; j++) {
            const int col = n0 + wn * 64 + j * 16 + ocol;
#pragma unroll
            for (int r = 0; r < 4; r++) {
                const int row = m0 + wm * 64 + i * 16 + orow + r;
                const float bvv = BIAS_ROW ? bias[row] : bias[col];
                const float v = acc[i][j][r] + bvv;
                if (OUT_BF16)
                    ((ushort_t*)Yv)[(size_t)row * N + col] = f2bf(v);
                else
                    ((float*)Yv)[(size_t)row * N + col] = v;
            }
        }
    }
}

// ---------------------------------------------------------------------------
// MFMA flash attention v3 (verified round 3: 102 us, MfmaUtil 14%):
// block-cooperative LDS-staged K/V (double-buffered, counted vmcnt),
// swapped-operand lane-local softmax, merged dual q-tiles, XCD-local (b,h).
// UNCHANGED this round.
// ---------------------------------------------------------------------------
__global__ __launch_bounds__(256, 2) void attn_mfma(
    const ushort_t* __restrict__ Qp,   // [B*S, H]
    const ushort_t* __restrict__ Kp,   // [B*S, H]
    const ushort_t* __restrict__ Vt,   // [H, B*S]
    const float*    __restrict__ mask, // [B, S] over key positions
    ushort_t* __restrict__ Op)         // [B*S, H]
{
    __shared__ ushort_t Kl[2][4096];     // [buf][64 rows x 64 elem] 8KB each
    __shared__ ushort_t Vl[2][4096];
    __shared__ ushort_t PlA[4][16 * 72]; // per-wave P^T slabs
    __shared__ ushort_t PlB[4][16 * 72];

    const int tid  = threadIdx.x;
    const int lane = tid & 63;
    const int wave = tid >> 6;
    const int li   = lane & 15;   // frag idx | C/D col (= q index)
    const int lq   = lane >> 4;   // quad
    const int blk  = blockIdx.x;
    // XCD-aware mapping: xcd = blk&7, 8 heads per XCD, 16 blocks per (b,h).
    const int xcd = blk & 7;
    const int jj  = blk >> 3;            // 0..127
    const int bh  = xcd * 8 + (jj & 7);  // 0..63
    const int pp  = jj >> 3;             // 0..15
    const int pr  = pp * 4 + wave;       // 0..63
    const int h   = bh & (NH - 1);
    const int b   = bh >> 4;
    const int prow = lq * 4;

    const int q0a = pr * 16;             // tile A (jmaxA = pp)
    const int q0b = (127 - pr) * 16;     // tile B (jmaxB = 31-pp)
    const int qrowA = q0a + li;
    const int qrowB = q0b + li;
    const int jmaxB = 31 - pp;

    const size_t bSEQ = (size_t)b * SEQ;
    const int    hoff = h * DH;

    // staging coords: row = tid>>3 (0..31, +32 on 2nd issue), chunk = tid&7,
    // source chunk pre-swizzled so LDS-linear dest == XOR-swizzled layout
    const int srow = tid >> 3;
    const int scs8 = ((tid & 7) ^ (srow & 7)) * 8;   // swizzled chunk * 8 elems

    // frag read offset (elements): row li (+nt*16), chunk0 = lq ^ (li&7)
    const int fr0 = li * 64 + ((lq ^ (li & 7)) * 8);

    ushort_t* pwA = &PlA[wave][0];
    ushort_t* pwB = &PlB[wave][0];

    const float* mbase = mask + bSEQ + prow;   // padding mask, indexed by key

    // persistent Q B-fragments
    const size_t qaA = (bSEQ + qrowA) * HID + hoff + lq * 8;
    const size_t qaB = (bSEQ + qrowB) * HID + hoff + lq * 8;
    const bf16x8 qfA0 = *(const bf16x8*)&Qp[qaA];
    const bf16x8 qfA1 = *(const bf16x8*)&Qp[qaA + 32];
    const bf16x8 qfB0 = *(const bf16x8*)&Qp[qaB];
    const bf16x8 qfB1 = *(const bf16x8*)&Qp[qaB + 32];

    f32x4 oaA[4], oaB[4];
#pragma unroll
    for (int nt = 0; nt < 4; nt++) {
        oaA[nt] = (f32x4){0.f, 0.f, 0.f, 0.f};
        oaB[nt] = (f32x4){0.f, 0.f, 0.f, 0.f};
    }
    float mA = -1e30f, lA = 0.f, mB = -1e30f, lB = 0.f;

    // stage tile js (keys js*64..+63) into buffer bs: 4 VMEM per thread
    auto STAGE = [&](int js, int bs) {
        const size_t k0s = (size_t)js * 64;
        const ushort_t* kg = Kp + (bSEQ + k0s + srow) * HID + hoff + scs8;
        ushort_t* kl = &Kl[bs][wave * 512];
        gload16(kg, kl);
        gload16(kg + (size_t)32 * HID, kl + 2048);
        const ushort_t* vg = Vt + (size_t)(hoff + srow) * MTOT + bSEQ + k0s + scs8;
        ushort_t* vl = &Vl[bs][wave * 512];
        gload16(vg, vl);
        gload16(vg + (size_t)32 * MTOT, vl + 2048);
    };

    STAGE(0, 0);   // prologue: 4 VMEM outstanding (+4 qf loads)

    for (int j = 0; j <= jmaxB; ++j) {
        const int  k0  = j * 64;
        const int  bs  = j & 1;
        const bool doA = (j <= pp);          // block-uniform

        // ---- padding mask, plain per-lane loads (pinned before STAGE) ----
        f32x4 mk[4];
#pragma unroll
        for (int nt = 0; nt < 4; nt++)
            mk[nt] = *(const f32x4*)&mbase[k0 + nt * 16];
        __builtin_amdgcn_sched_barrier(0);

        // ---- prefetch next tile (never drained this iteration: T4) ----
        const int jn = (j < jmaxB) ? (j + 1) : jmaxB;
        STAGE(jn, bs ^ 1);

        // outstanding: stage(j)=4 (oldest) + mask=4 + stage(j+1)=4 -> wait
        // until <=8 completes exactly stage(j); stage(j+1)+mask stay in flight
        asm volatile("s_waitcnt vmcnt(8)" ::: "memory");
        __builtin_amdgcn_s_barrier();
        __builtin_amdgcn_sched_barrier(0);

        // ---- K fragments from LDS (swizzled) ----
        bf16x8 kf[4][2];
#pragma unroll
        for (int nt = 0; nt < 4; nt++) {
            const int eo = nt * 1024 + fr0;
            kf[nt][0] = *(const bf16x8*)&Kl[bs][eo];
            kf[nt][1] = *(const bf16x8*)&Kl[bs][eo ^ 32];
        }

        // ---- S^T = K Q^T for both q-tiles ----
        f32x4 saA[4], saB[4];
        __builtin_amdgcn_s_setprio(1);
#pragma unroll
        for (int nt = 0; nt < 4; nt++) {
            f32x4 a = (f32x4){0.f, 0.f, 0.f, 0.f};
            a = __builtin_amdgcn_mfma_f32_16x16x32_bf16(kf[nt][0], qfB0, a, 0, 0, 0);
            a = __builtin_amdgcn_mfma_f32_16x16x32_bf16(kf[nt][1], qfB1, a, 0, 0, 0);
            saB[nt] = a;
        }
        if (doA) {
#pragma unroll
            for (int nt = 0; nt < 4; nt++) {
                f32x4 a = (f32x4){0.f, 0.f, 0.f, 0.f};
                a = __builtin_amdgcn_mfma_f32_16x16x32_bf16(kf[nt][0], qfA0, a, 0, 0, 0);
                a = __builtin_amdgcn_mfma_f32_16x16x32_bf16(kf[nt][1], qfA1, a, 0, 0, 0);
                saA[nt] = a;
            }
        }
        __builtin_amdgcn_s_setprio(0);

        // ---- tile B: scale + mask + online softmax (lane-local row) ----
        float sB[4][4];
#pragma unroll
        for (int nt = 0; nt < 4; nt++)
#pragma unroll
            for (int r = 0; r < 4; r++) {
                const float v = saB[nt][r] * 0.125f;
                sB[nt][r] = (mk[nt][r] == 0.f) ? FILLV : v;
            }
        if (k0 + 63 > q0b) {
#pragma unroll
            for (int nt = 0; nt < 4; nt++)
#pragma unroll
                for (int r = 0; r < 4; r++) {
                    const int kpos = k0 + nt * 16 + prow + r;
                    sB[nt][r] = (kpos > qrowB) ? FILLV : sB[nt][r];
                }
        }
        float pmB = fmaxf(fmaxf(sB[0][0], sB[0][1]), fmaxf(sB[0][2], sB[0][3]));
#pragma unroll
        for (int nt = 1; nt < 4; nt++)
            pmB = fmaxf(pmB, fmaxf(fmaxf(sB[nt][0], sB[nt][1]),
                                   fmaxf(sB[nt][2], sB[nt][3])));
        pmB = fmaxf(pmB, __shfl_xor(pmB, 16));
        pmB = fmaxf(pmB, __shfl_xor(pmB, 32));
        const float mnB = fmaxf(mB, pmB);
        const float alB = __expf(mB - mnB);
        mB = mnB;
        float psB = 0.f;
#pragma unroll
        for (int nt = 0; nt < 4; nt++) {
            const float p0 = __expf(sB[nt][0] - mnB);
            const float p1 = __expf(sB[nt][1] - mnB);
            const float p2 = __expf(sB[nt][2] - mnB);
            const float p3 = __expf(sB[nt][3] - mnB);
            psB += (p0 + p1) + (p2 + p3);
            ushort4 pk;
            pk.x = f2bf(p0); pk.y = f2bf(p1); pk.z = f2bf(p2); pk.w = f2bf(p3);
            *(ushort4*)&pwB[li * 72 + nt * 16 + prow] = pk;
        }
        psB += __shfl_xor(psB, 16);
        psB += __shfl_xor(psB, 32);
        lB = lB * alB + psB;

        // ---- tile A softmax (only while active) ----
        float alA = 1.f;
        if (doA) {
            float sA[4][4];
#pragma unroll
            for (int nt = 0; nt < 4; nt++)
#pragma unroll
                for (int r = 0; r < 4; r++) {
                    const float v = saA[nt][r] * 0.125f;
                    sA[nt][r] = (mk[nt][r] == 0.f) ? FILLV : v;
                }
            if (k0 + 63 > q0a) {
#pragma unroll
                for (int nt = 0; nt < 4; nt++)
#pragma unroll
                    for (int r = 0; r < 4; r++) {
                        const int kpos = k0 + nt * 16 + prow + r;
                        sA[nt][r] = (kpos > qrowA) ? FILLV : sA[nt][r];
                    }
            }
            float pmA = fmaxf(fmaxf(sA[0][0], sA[0][1]), fmaxf(sA[0][2], sA[0][3]));
#pragma unroll
            for (int nt = 1; nt < 4; nt++)
                pmA = fmaxf(pmA, fmaxf(fmaxf(sA[nt][0], sA[nt][1]),
                                       fmaxf(sA[nt][2], sA[nt][3])));
            pmA = fmaxf(pmA, __shfl_xor(pmA, 16));
            pmA = fmaxf(pmA, __shfl_xor(pmA, 32));
            const float mnA = fmaxf(mA, pmA);
            alA = __expf(mA - mnA);
            mA = mnA;
            float psA = 0.f;
#pragma unroll
            for (int nt = 0; nt < 4; nt++) {
                const float p0 = __expf(sA[nt][0] - mnA);
                const float p1 = __expf(sA[nt][1] - mnA);
                const float p2 = __expf(sA[nt][2] - mnA);
                const float p3 = __expf(sA[nt][3] - mnA);
                psA += (p0 + p1) + (p2 + p3);
                ushort4 pk;
                pk.x = f2bf(p0); pk.y = f2bf(p1); pk.z = f2bf(p2); pk.w = f2bf(p3);
                *(ushort4*)&pwA[li * 72 + nt * 16 + prow] = pk;
            }
            psA += __shfl_xor(psA, 16);
            psA += __shfl_xor(psA, 32);
            lA = lA * alA + psA;
        }

        // ---- V fragments + P fragments ----
        const bf16x8 pfB0 = *(const bf16x8*)&pwB[li * 72 + lq * 8];
        const bf16x8 pfB1 = *(const bf16x8*)&pwB[li * 72 + 32 + lq * 8];
        bf16x8 vf[4][2];
#pragma unroll
        for (int nt = 0; nt < 4; nt++) {
            const int eo = nt * 1024 + fr0;
            vf[nt][0] = *(const bf16x8*)&Vl[bs][eo];
            vf[nt][1] = *(const bf16x8*)&Vl[bs][eo ^ 32];
        }

        // ---- O^T += V^T P^T ----
        __builtin_amdgcn_s_setprio(1);
#pragma unroll
        for (int nt = 0; nt < 4; nt++) {
            f32x4 o = oaB[nt];
#pragma unroll
            for (int r = 0; r < 4; r++) o[r] *= alB;
            o = __builtin_amdgcn_mfma_f32_16x16x32_bf16(vf[nt][0], pfB0, o, 0, 0, 0);
            o = __builtin_amdgcn_mfma_f32_16x16x32_bf16(vf[nt][1], pfB1, o, 0, 0, 0);
            oaB[nt] = o;
        }
        __builtin_amdgcn_s_setprio(0);
        if (doA) {
            const bf16x8 pfA0 = *(const bf16x8*)&pwA[li * 72 + lq * 8];
            const bf16x8 pfA1 = *(const bf16x8*)&pwA[li * 72 + 32 + lq * 8];
            __builtin_amdgcn_s_setprio(1);
#pragma unroll
            for (int nt = 0; nt < 4; nt++) {
                f32x4 o = oaA[nt];
#pragma unroll
                for (int r = 0; r < 4; r++) o[r] *= alA;
                o = __builtin_amdgcn_mfma_f32_16x16x32_bf16(vf[nt][0], pfA0, o, 0, 0, 0);
                o = __builtin_amdgcn_mfma_f32_16x16x32_bf16(vf[nt][1], pfA1, o, 0, 0, 0);
                oaA[nt] = o;
            }
            __builtin_amdgcn_s_setprio(0);
        }

        // all waves done READING buf[bs] before next iter's STAGE overwrites it
        __builtin_amdgcn_sched_barrier(0);
        __builtin_amdgcn_s_barrier();
    }
    // drain the redundant last prefetch before s_endpgm (LDS writes in flight)
    asm volatile("s_waitcnt vmcnt(0)" ::: "memory");

    // ---- normalize + packed bf16 stores ----
    {
        const float linv = 1.f / lB;
        const size_t obase = (bSEQ + qrowB) * HID + hoff + prow;
#pragma unroll
        for (int nt = 0; nt < 4; nt++) {
            ushort4 ov;
            ov.x = f2bf(oaB[nt][0] * linv);
            ov.y = f2bf(oaB[nt][1] * linv);
            ov.z = f2bf(oaB[nt][2] * linv);
            ov.w = f2bf(oaB[nt][3] * linv);
            *(ushort4*)&Op[obase + nt * 16] = ov;
        }
    }
    {
        const float linv = 1.f / lA;
        const size_t obase = (bSEQ + qrowA) * HID + hoff + prow;
#pragma unroll
        for (int nt = 0; nt < 4; nt++) {
            ushort4 ov;
            ov.x = f2bf(oaA[nt][0] * linv);
            ov.y = f2bf(oaA[nt][1] * linv);
            ov.z = f2bf(oaA[nt][2] * linv);
            ov.w = f2bf(oaA[nt][3] * linv);
            *(ushort4*)&Op[obase + nt * 16] = ov;
        }
    }
}

// ---------------------------------------------------------------------------
extern "C" void kernel_launch(void* const* d_in, const int* in_sizes, int n_in,
                              void* d_out, int out_size, void* d_ws, size_t ws_size,
                              hipStream_t stream) {
    const float* query = (const float*)d_in[0];
    const float* key   = (const float*)d_in[1];
    const float* value = (const float*)d_in[2];
    const float* mask  = (const float*)d_in[3];
    const float* Wq    = (const float*)d_in[4];
    const float* bq    = (const float*)d_in[5];
    const float* Wk    = (const float*)d_in[6];
    const float* bk    = (const float*)d_in[7];
    const float* Wv    = (const float*)d_in[8];
    const float* bv    = (const float*)d_in[9];
    const float* Wo    = (const float*)d_in[10];
    const float* bo    = (const float*)d_in[11];

    // workspace (bf16): 7 activation-size buffers + 4 weight buffers ≈ 125.5 MB
    const size_t eA = (size_t)MTOT * HID;
    const size_t eW = (size_t)HID * HID;
    ushort_t* qb  = (ushort_t*)d_ws;
    ushort_t* kb  = qb  + eA;
    ushort_t* vb  = kb  + eA;
    ushort_t* Qp  = vb  + eA;
    ushort_t* Kp  = Qp  + eA;
    ushort_t* Vtb = Kp  + eA;   // [H, B*S]
    ushort_t* Op  = Vtb + eA;
    ushort_t* wqb = Op  + eA;
    ushort_t* wkb = wqb + eW;
    ushort_t* wvb = wkb + eW;
    ushort_t* wob = wvb + eW;

    const int n4a = (int)(eA / 4), n4w = (int)(eW / 4);
    cast_f32_bf16<<<(n4a + 255) / 256, 256, 0, stream>>>(query, qb, n4a);
    cast_f32_bf16<<<(n4a + 255) / 256, 256, 0, stream>>>(key,   kb, n4a);
    cast_f32_bf16<<<(n4a + 255) / 256, 256, 0, stream>>>(value, vb, n4a);
    cast_f32_bf16<<<(n4w + 255) / 256, 256, 0, stream>>>(Wq, wqb, n4w);
    cast_f32_bf16<<<(n4w + 255) / 256, 256, 0, stream>>>(Wk, wkb, n4w);
    cast_f32_bf16<<<(n4w + 255) / 256, 256, 0, stream>>>(Wv, wvb, n4w);
    cast_f32_bf16<<<(n4w + 255) / 256, 256, 0, stream>>>(Wo, wob, n4w);

    dim3 gg(HID / 128, MTOT / 128);   // (8, 64)
    gemm_bt_mfma<true, false><<<gg, 256, 0, stream>>>(qb, wqb, bq, Qp, MTOT, HID, HID);
    gemm_bt_mfma<true, false><<<gg, 256, 0, stream>>>(kb, wkb, bk, Kp, MTOT, HID, HID);
    // Vt = Wv @ value^T  -> [H, B*S], bias by row (bv[d])
    dim3 gv(MTOT / 128, HID / 128);   // (64, 8)
    gemm_bt_mfma<true, true><<<gv, 256, 0, stream>>>(wvb, vb, bv, Vtb, HID, MTOT, HID);

    // flash attention: 1024 blocks, 4 waves each, XCD-local (b,h)
    attn_mfma<<<(BATCH * NH * 64) / 4, 256, 0, stream>>>(Qp, Kp, Vtb, mask, Op);

    gemm_bt_mfma<false, false><<<gg, 256, 0, stream>>>(Op, wob, bo, d_out, MTOT, HID, HID);
}

// Round 5
// 398.177 us; speedup vs baseline: 2.3343x; 1.0345x over previous
//
#include <hip/hip_runtime.h>
#include <hip/hip_bf16.h>
#include <math.h>

// Problem constants: B=4, S=2048, H=1024, nh=16, dh=64.
#define BATCH 4
#define SEQ   2048
#define HID   1024
#define NH    16
#define DH    64
#define MTOT  (BATCH * SEQ)   // 8192
#define FILLV (-1e13f)
#define N4A   (MTOT * HID / 4)   // 2^21 float4-groups per activation buffer
#define N4W   (HID * HID / 4)    // 2^18 per weight buffer

typedef unsigned short ushort_t;
typedef short bf16x8 __attribute__((ext_vector_type(8)));
typedef float f32x4  __attribute__((ext_vector_type(4)));

__device__ __forceinline__ float bf2f(ushort_t u) {
    return __uint_as_float(((unsigned int)u) << 16);
}
__device__ __forceinline__ ushort_t f2bf(float f) {
    union { __hip_bfloat16 h; ushort_t u; } cv;
    cv.h = __float2bfloat16(f);
    return cv.u;
}

// async global->LDS, 16B per lane; LDS dest = wave-uniform base + lane*16
__device__ __forceinline__ void gload16(const void* g, void* l) {
    __builtin_amdgcn_global_load_lds(
        (const __attribute__((address_space(1))) unsigned int*)g,
        (__attribute__((address_space(3))) unsigned int*)l, 16, 0, 0);
}

__device__ __forceinline__ ushort4 cvt4(const float4 v) {
    ushort4 o;
    o.x = f2bf(v.x); o.y = f2bf(v.y); o.z = f2bf(v.z); o.w = f2bf(v.w);
    return o;
}

// ---------------------------------------------------------------------------
// fused fp32->bf16 casts: 3 activation buffers -> contiguous dst (qb,kb,vb)
// ---------------------------------------------------------------------------
__global__ __launch_bounds__(256) void cast3_act(
    const float* __restrict__ s0, const float* __restrict__ s1,
    const float* __restrict__ s2, ushort_t* __restrict__ dst)
{
    const int i   = blockIdx.x * 256 + threadIdx.x;      // < 3*N4A
    const int seg = i >> 21;                             // block-uniform
    const int off = i & (N4A - 1);
    const float* s = (seg == 0) ? s0 : (seg == 1) ? s1 : s2;
    ((ushort4*)dst)[i] = cvt4(((const float4*)s)[off]);
}

// 4 weight buffers -> contiguous dst (wqb,wkb,wvb,wob)
__global__ __launch_bounds__(256) void cast4_w(
    const float* __restrict__ s0, const float* __restrict__ s1,
    const float* __restrict__ s2, const float* __restrict__ s3,
    ushort_t* __restrict__ dst)
{
    const int i   = blockIdx.x * 256 + threadIdx.x;      // < 4*N4W
    const int seg = i >> 18;
    const int off = i & (N4W - 1);
    const float* s = (seg == 0) ? s0 : (seg == 1) ? s1 : (seg == 2) ? s2 : s3;
    ((ushort4*)dst)[i] = cvt4(((const float4*)s)[off]);
}

// ---------------------------------------------------------------------------
// FUSED QKV-projection GEMM: one 1536-block dispatch, z selects the GEMM.
//  z=0: Qp  = qb  @ Wq^T + bq   [M=8192,N=1024]  (col bias)
//  z=1: Kp  = kb  @ Wk^T + bk   [M=8192,N=1024]  (col bias)
//  z=2: Vtb = wvb @ vb^T + bv   [M=1024,N=8192]  (row bias)
// All share K=1024 (compile-time strides). Inner loop identical to the
// verified double-buffered counted-vmcnt loop.
// WHY: round-4 showed each 512-block GEMM runs at 2 blocks/CU while HW can
// host 4 (VGPR/LDS limits) -> stall-dominated (~250 TF). 1536 blocks gives
// 4/CU co-residency; cross-block overlap hides staging latency (m114).
// ---------------------------------------------------------------------------
__global__ __launch_bounds__(256) void qkv_gemm(
    const ushort_t* __restrict__ A0, const ushort_t* __restrict__ A1,
    const ushort_t* __restrict__ A2,
    const ushort_t* __restrict__ W0, const ushort_t* __restrict__ W1,
    const ushort_t* __restrict__ W2,
    const float* __restrict__ b0, const float* __restrict__ b1,
    const float* __restrict__ b2,
    ushort_t* __restrict__ Y0, ushort_t* __restrict__ Y1,
    ushort_t* __restrict__ Y2)
{
    __shared__ ushort_t As[2][4096];
    __shared__ ushort_t Bs[2][4096];

    const int z = blockIdx.z;
    const ushort_t* A    = (z == 0) ? A0 : (z == 1) ? A1 : A2;
    const ushort_t* W    = (z == 0) ? W0 : (z == 1) ? W1 : W2;
    const float*    bias = (z == 0) ? b0 : (z == 1) ? b1 : b2;
    ushort_t*       Y    = (z == 0) ? Y0 : (z == 1) ? Y1 : Y2;
    const int  Nz   = (z == 2) ? MTOT : HID;
    const int  gx   = Nz >> 7;            // n-blocks: 64 or 8
    const bool brow = (z == 2);

    const int tid  = threadIdx.x;
    const int lane = tid & 63;
    const int wave = tid >> 6;
    const int wm   = wave & 1;
    const int wn   = wave >> 1;

    // XCD-chunked bijective swizzle within this z-slice (512 blocks, 64/XCD).
    // Dispatch linearizes z*512+x; 512%8==0 so xcd = flat&7 holds per-slice.
    const int flat = blockIdx.x;
    const int fl2  = (flat & 7) * 64 + (flat >> 3);
    const int bx   = fl2 % gx;
    const int by   = fl2 / gx;

    const int m0   = by * 128;
    const int n0   = bx * 128;
    const int lr   = lane & 15;
    const int lk   = (lane >> 4) * 8;

    f32x4 acc[4][4];
#pragma unroll
    for (int i = 0; i < 4; i++)
#pragma unroll
        for (int j = 0; j < 4; j++) acc[i][j] = (f32x4){0.f, 0.f, 0.f, 0.f};

    // stage K-chunk kk into buffer d (4 VMEM per thread); K = HID = 1024
    auto STAGE = [&](int kk, int d) {
        const ushort_t* a = A + (size_t)(m0 + wave * 32 + lr) * HID + kk + lk;
        const ushort_t* w = W + (size_t)(n0 + wave * 32 + lr) * HID + kk + lk;
        ushort_t* al = &As[d][wave * 1024];
        ushort_t* bl = &Bs[d][wave * 1024];
        gload16(a,            al);
        gload16(a + 16 * HID, al + 512);
        gload16(w,            bl);
        gload16(w + 16 * HID, bl + 512);
    };

    const int nk = HID >> 5;   // 32
    STAGE(0, 0);

    for (int kt = 0; kt < nk; ++kt) {
        const int d = kt & 1;
        if (kt + 1 < nk) {
            STAGE((kt + 1) << 5, d ^ 1);
            asm volatile("s_waitcnt vmcnt(4)" ::: "memory");
        } else {
            asm volatile("s_waitcnt vmcnt(0)" ::: "memory");
        }
        __builtin_amdgcn_s_barrier();
        __builtin_amdgcn_sched_barrier(0);

        bf16x8 af[4], bf[4];
#pragma unroll
        for (int i = 0; i < 4; i++)
            af[i] = *(const bf16x8*)&As[d][(wm * 4 + i) * 512 + lane * 8];
#pragma unroll
        for (int j = 0; j < 4; j++)
            bf[j] = *(const bf16x8*)&Bs[d][(wn * 4 + j) * 512 + lane * 8];
#pragma unroll
        for (int i = 0; i < 4; i++)
#pragma unroll
            for (int j = 0; j < 4; j++)
                acc[i][j] = __builtin_amdgcn_mfma_f32_16x16x32_bf16(
                    af[i], bf[j], acc[i][j], 0, 0, 0);

        __builtin_amdgcn_sched_barrier(0);
        __builtin_amdgcn_s_barrier();
    }

    const int orow = (lane >> 4) * 4;
    const int ocol = lane & 15;
#pragma unroll
    for (int i = 0; i < 4; i++) {
#pragma unroll
        for (int j = 0; j < 4; j++) {
            const int col = n0 + wn * 64 + j * 16 + ocol;
#pragma unroll
            for (int r = 0; r < 4; r++) {
                const int row = m0 + wm * 64 + i * 16 + orow + r;
                const float bvv = brow ? bias[row] : bias[col];
                Y[(size_t)row * Nz + col] = f2bf(acc[i][j][r] + bvv);
            }
        }
    }
}

// ---------------------------------------------------------------------------
// O-projection GEMM (fp32 out), round-4 verified structure. UNCHANGED.
// ---------------------------------------------------------------------------
__global__ __launch_bounds__(256) void gemm_o(
    const ushort_t* __restrict__ A,   // [M,K] bf16
    const ushort_t* __restrict__ W,   // [N,K] bf16
    const float*    __restrict__ bias,
    float* __restrict__ Yv,           // [M,N] fp32
    int M, int N, int K)
{
    __shared__ ushort_t As[2][4096];
    __shared__ ushort_t Bs[2][4096];

    const int tid  = threadIdx.x;
    const int lane = tid & 63;
    const int wave = tid >> 6;
    const int wm   = wave & 1;
    const int wn   = wave >> 1;

    const int flat = blockIdx.y * gridDim.x + blockIdx.x;
    const int cpx  = (gridDim.x * gridDim.y) >> 3;
    const int fl2  = (flat & 7) * cpx + (flat >> 3);
    const int bx   = fl2 % gridDim.x;
    const int by   = fl2 / gridDim.x;

    const int m0   = by * 128;
    const int n0   = bx * 128;
    const int lr   = lane & 15;
    const int lk   = (lane >> 4) * 8;

    f32x4 acc[4][4];
#pragma unroll
    for (int i = 0; i < 4; i++)
#pragma unroll
        for (int j = 0; j < 4; j++) acc[i][j] = (f32x4){0.f, 0.f, 0.f, 0.f};

    auto STAGE = [&](int kk, int d) {
        const ushort_t* a = A + (size_t)(m0 + wave * 32 + lr) * K + kk + lk;
        const ushort_t* w = W + (size_t)(n0 + wave * 32 + lr) * K + kk + lk;
        ushort_t* al = &As[d][wave * 1024];
        ushort_t* bl = &Bs[d][wave * 1024];
        gload16(a,                  al);
        gload16(a + (size_t)16 * K, al + 512);
        gload16(w,                  bl);
        gload16(w + (size_t)16 * K, bl + 512);
    };

    const int nk = K >> 5;
    STAGE(0, 0);

    for (int kt = 0; kt < nk; ++kt) {
        const int d = kt & 1;
        if (kt + 1 < nk) {
            STAGE((kt + 1) << 5, d ^ 1);
            asm volatile("s_waitcnt vmcnt(4)" ::: "memory");
        } else {
            asm volatile("s_waitcnt vmcnt(0)" ::: "memory");
        }
        __builtin_amdgcn_s_barrier();
        __builtin_amdgcn_sched_barrier(0);

        bf16x8 af[4], bf[4];
#pragma unroll
        for (int i = 0; i < 4; i++)
            af[i] = *(const bf16x8*)&As[d][(wm * 4 + i) * 512 + lane * 8];
#pragma unroll
        for (int j = 0; j < 4; j++)
            bf[j] = *(const bf16x8*)&Bs[d][(wn * 4 + j) * 512 + lane * 8];
#pragma unroll
        for (int i = 0; i < 4; i++)
#pragma unroll
            for (int j = 0; j < 4; j++)
                acc[i][j] = __builtin_amdgcn_mfma_f32_16x16x32_bf16(
                    af[i], bf[j], acc[i][j], 0, 0, 0);

        __builtin_amdgcn_sched_barrier(0);
        __builtin_amdgcn_s_barrier();
    }

    const int orow = (lane >> 4) * 4;
    const int ocol = lane & 15;
#pragma unroll
    for (int i = 0; i < 4; i++) {
#pragma unroll
        for (int j = 0; j < 4; j++) {
            const int col = n0 + wn * 64 + j * 16 + ocol;
#pragma unroll
            for (int r = 0; r < 4; r++) {
                const int row = m0 + wm * 64 + i * 16 + orow + r;
                Yv[(size_t)row * N + col] = acc[i][j][r] + bias[col];
            }
        }
    }
}

// ---------------------------------------------------------------------------
// MFMA flash attention v3 (verified round 3: ~102-107 us): block-cooperative
// LDS-staged K/V (double-buffered, counted vmcnt), swapped-operand lane-local
// softmax, merged dual q-tiles, XCD-local (b,h). UNCHANGED.
// ---------------------------------------------------------------------------
__global__ __launch_bounds__(256, 2) void attn_mfma(
    const ushort_t* __restrict__ Qp,   // [B*S, H]
    const ushort_t* __restrict__ Kp,   // [B*S, H]
    const ushort_t* __restrict__ Vt,   // [H, B*S]
    const float*    __restrict__ mask, // [B, S] over key positions
    ushort_t* __restrict__ Op)         // [B*S, H]
{
    __shared__ ushort_t Kl[2][4096];     // [buf][64 rows x 64 elem] 8KB each
    __shared__ ushort_t Vl[2][4096];
    __shared__ ushort_t PlA[4][16 * 72]; // per-wave P^T slabs
    __shared__ ushort_t PlB[4][16 * 72];

    const int tid  = threadIdx.x;
    const int lane = tid & 63;
    const int wave = tid >> 6;
    const int li   = lane & 15;   // frag idx | C/D col (= q index)
    const int lq   = lane >> 4;   // quad
    const int blk  = blockIdx.x;
    const int xcd = blk & 7;
    const int jj  = blk >> 3;            // 0..127
    const int bh  = xcd * 8 + (jj & 7);  // 0..63
    const int pp  = jj >> 3;             // 0..15
    const int pr  = pp * 4 + wave;       // 0..63
    const int h   = bh & (NH - 1);
    const int b   = bh >> 4;
    const int prow = lq * 4;

    const int q0a = pr * 16;             // tile A (jmaxA = pp)
    const int q0b = (127 - pr) * 16;     // tile B (jmaxB = 31-pp)
    const int qrowA = q0a + li;
    const int qrowB = q0b + li;
    const int jmaxB = 31 - pp;

    const size_t bSEQ = (size_t)b * SEQ;
    const int    hoff = h * DH;

    const int srow = tid >> 3;
    const int scs8 = ((tid & 7) ^ (srow & 7)) * 8;   // swizzled chunk * 8 elems

    const int fr0 = li * 64 + ((lq ^ (li & 7)) * 8);

    ushort_t* pwA = &PlA[wave][0];
    ushort_t* pwB = &PlB[wave][0];

    const float* mbase = mask + bSEQ + prow;   // padding mask, indexed by key

    const size_t qaA = (bSEQ + qrowA) * HID + hoff + lq * 8;
    const size_t qaB = (bSEQ + qrowB) * HID + hoff + lq * 8;
    const bf16x8 qfA0 = *(const bf16x8*)&Qp[qaA];
    const bf16x8 qfA1 = *(const bf16x8*)&Qp[qaA + 32];
    const bf16x8 qfB0 = *(const bf16x8*)&Qp[qaB];
    const bf16x8 qfB1 = *(const bf16x8*)&Qp[qaB + 32];

    f32x4 oaA[4], oaB[4];
#pragma unroll
    for (int nt = 0; nt < 4; nt++) {
        oaA[nt] = (f32x4){0.f, 0.f, 0.f, 0.f};
        oaB[nt] = (f32x4){0.f, 0.f, 0.f, 0.f};
    }
    float mA = -1e30f, lA = 0.f, mB = -1e30f, lB = 0.f;

    auto STAGE = [&](int js, int bs) {
        const size_t k0s = (size_t)js * 64;
        const ushort_t* kg = Kp + (bSEQ + k0s + srow) * HID + hoff + scs8;
        ushort_t* kl = &Kl[bs][wave * 512];
        gload16(kg, kl);
        gload16(kg + (size_t)32 * HID, kl + 2048);
        const ushort_t* vg = Vt + (size_t)(hoff + srow) * MTOT + bSEQ + k0s + scs8;
        ushort_t* vl = &Vl[bs][wave * 512];
        gload16(vg, vl);
        gload16(vg + (size_t)32 * MTOT, vl + 2048);
    };

    STAGE(0, 0);

    for (int j = 0; j <= jmaxB; ++j) {
        const int  k0  = j * 64;
        const int  bs  = j & 1;
        const bool doA = (j <= pp);          // block-uniform

        f32x4 mk[4];
#pragma unroll
        for (int nt = 0; nt < 4; nt++)
            mk[nt] = *(const f32x4*)&mbase[k0 + nt * 16];
        __builtin_amdgcn_sched_barrier(0);

        const int jn = (j < jmaxB) ? (j + 1) : jmaxB;
        STAGE(jn, bs ^ 1);

        asm volatile("s_waitcnt vmcnt(8)" ::: "memory");
        __builtin_amdgcn_s_barrier();
        __builtin_amdgcn_sched_barrier(0);

        bf16x8 kf[4][2];
#pragma unroll
        for (int nt = 0; nt < 4; nt++) {
            const int eo = nt * 1024 + fr0;
            kf[nt][0] = *(const bf16x8*)&Kl[bs][eo];
            kf[nt][1] = *(const bf16x8*)&Kl[bs][eo ^ 32];
        }

        f32x4 saA[4], saB[4];
        __builtin_amdgcn_s_setprio(1);
#pragma unroll
        for (int nt = 0; nt < 4; nt++) {
            f32x4 a = (f32x4){0.f, 0.f, 0.f, 0.f};
            a = __builtin_amdgcn_mfma_f32_16x16x32_bf16(kf[nt][0], qfB0, a, 0, 0, 0);
            a = __builtin_amdgcn_mfma_f32_16x16x32_bf16(kf[nt][1], qfB1, a, 0, 0, 0);
            saB[nt] = a;
        }
        if (doA) {
#pragma unroll
            for (int nt = 0; nt < 4; nt++) {
                f32x4 a = (f32x4){0.f, 0.f, 0.f, 0.f};
                a = __builtin_amdgcn_mfma_f32_16x16x32_bf16(kf[nt][0], qfA0, a, 0, 0, 0);
                a = __builtin_amdgcn_mfma_f32_16x16x32_bf16(kf[nt][1], qfA1, a, 0, 0, 0);
                saA[nt] = a;
            }
        }
        __builtin_amdgcn_s_setprio(0);

        float sB[4][4];
#pragma unroll
        for (int nt = 0; nt < 4; nt++)
#pragma unroll
            for (int r = 0; r < 4; r++) {
                const float v = saB[nt][r] * 0.125f;
                sB[nt][r] = (mk[nt][r] == 0.f) ? FILLV : v;
            }
        if (k0 + 63 > q0b) {
#pragma unroll
            for (int nt = 0; nt < 4; nt++)
#pragma unroll
                for (int r = 0; r < 4; r++) {
                    const int kpos = k0 + nt * 16 + prow + r;
                    sB[nt][r] = (kpos > qrowB) ? FILLV : sB[nt][r];
                }
        }
        float pmB = fmaxf(fmaxf(sB[0][0], sB[0][1]), fmaxf(sB[0][2], sB[0][3]));
#pragma unroll
        for (int nt = 1; nt < 4; nt++)
            pmB = fmaxf(pmB, fmaxf(fmaxf(sB[nt][0], sB[nt][1]),
                                   fmaxf(sB[nt][2], sB[nt][3])));
        pmB = fmaxf(pmB, __shfl_xor(pmB, 16));
        pmB = fmaxf(pmB, __shfl_xor(pmB, 32));
        const float mnB = fmaxf(mB, pmB);
        const float alB = __expf(mB - mnB);
        mB = mnB;
        float psB = 0.f;
#pragma unroll
        for (int nt = 0; nt < 4; nt++) {
            const float p0 = __expf(sB[nt][0] - mnB);
            const float p1 = __expf(sB[nt][1] - mnB);
            const float p2 = __expf(sB[nt][2] - mnB);
            const float p3 = __expf(sB[nt][3] - mnB);
            psB += (p0 + p1) + (p2 + p3);
            ushort4 pk;
            pk.x = f2bf(p0); pk.y = f2bf(p1); pk.z = f2bf(p2); pk.w = f2bf(p3);
            *(ushort4*)&pwB[li * 72 + nt * 16 + prow] = pk;
        }
        psB += __shfl_xor(psB, 16);
        psB += __shfl_xor(psB, 32);
        lB = lB * alB + psB;

        float alA = 1.f;
        if (doA) {
            float sA[4][4];
#pragma unroll
            for (int nt = 0; nt < 4; nt++)
#pragma unroll
                for (int r = 0; r < 4; r++) {
                    const float v = saA[nt][r] * 0.125f;
                    sA[nt][r] = (mk[nt][r] == 0.f) ? FILLV : v;
                }
            if (k0 + 63 > q0a) {
#pragma unroll
                for (int nt = 0; nt < 4; nt++)
#pragma unroll
                    for (int r = 0; r < 4; r++) {
                        const int kpos = k0 + nt * 16 + prow + r;
                        sA[nt][r] = (kpos > qrowA) ? FILLV : sA[nt][r];
                    }
            }
            float pmA = fmaxf(fmaxf(sA[0][0], sA[0][1]), fmaxf(sA[0][2], sA[0][3]));
#pragma unroll
            for (int nt = 1; nt < 4; nt++)
                pmA = fmaxf(pmA, fmaxf(fmaxf(sA[nt][0], sA[nt][1]),
                                       fmaxf(sA[nt][2], sA[nt][3])));
            pmA = fmaxf(pmA, __shfl_xor(pmA, 16));
            pmA = fmaxf(pmA, __shfl_xor(pmA, 32));
            const float mnA = fmaxf(mA, pmA);
            alA = __expf(mA - mnA);
            mA = mnA;
            float psA = 0.f;
#pragma unroll
            for (int nt = 0; nt < 4; nt++) {
                const float p0 = __expf(sA[nt][0] - mnA);
                const float p1 = __expf(sA[nt][1] - mnA);
                const float p2 = __expf(sA[nt][2] - mnA);
                const float p3 = __expf(sA[nt][3] - mnA);
                psA += (p0 + p1) + (p2 + p3);
                ushort4 pk;
                pk.x = f2bf(p0); pk.y = f2bf(p1); pk.z = f2bf(p2); pk.w = f2bf(p3);
                *(ushort4*)&pwA[li * 72 + nt * 16 + prow] = pk;
            }
            psA += __shfl_xor(psA, 16);
            psA += __shfl_xor(psA, 32);
            lA = lA * alA + psA;
        }

        const bf16x8 pfB0 = *(const bf16x8*)&pwB[li * 72 + lq * 8];
        const bf16x8 pfB1 = *(const bf16x8*)&pwB[li * 72 + 32 + lq * 8];
        bf16x8 vf[4][2];
#pragma unroll
        for (int nt = 0; nt < 4; nt++) {
            const int eo = nt * 1024 + fr0;
            vf[nt][0] = *(const bf16x8*)&Vl[bs][eo];
            vf[nt][1] = *(const bf16x8*)&Vl[bs][eo ^ 32];
        }

        __builtin_amdgcn_s_setprio(1);
#pragma unroll
        for (int nt = 0; nt < 4; nt++) {
            f32x4 o = oaB[nt];
#pragma unroll
            for (int r = 0; r < 4; r++) o[r] *= alB;
            o = __builtin_amdgcn_mfma_f32_16x16x32_bf16(vf[nt][0], pfB0, o, 0, 0, 0);
            o = __builtin_amdgcn_mfma_f32_16x16x32_bf16(vf[nt][1], pfB1, o, 0, 0, 0);
            oaB[nt] = o;
        }
        __builtin_amdgcn_s_setprio(0);
        if (doA) {
            const bf16x8 pfA0 = *(const bf16x8*)&pwA[li * 72 + lq * 8];
            const bf16x8 pfA1 = *(const bf16x8*)&pwA[li * 72 + 32 + lq * 8];
            __builtin_amdgcn_s_setprio(1);
#pragma unroll
            for (int nt = 0; nt < 4; nt++) {
                f32x4 o = oaA[nt];
#pragma unroll
                for (int r = 0; r < 4; r++) o[r] *= alA;
                o = __builtin_amdgcn_mfma_f32_16x16x32_bf16(vf[nt][0], pfA0, o, 0, 0, 0);
                o = __builtin_amdgcn_mfma_f32_16x16x32_bf16(vf[nt][1], pfA1, o, 0, 0, 0);
                oaA[nt] = o;
            }
            __builtin_amdgcn_s_setprio(0);
        }

        __builtin_amdgcn_sched_barrier(0);
        __builtin_amdgcn_s_barrier();
    }
    asm volatile("s_waitcnt vmcnt(0)" ::: "memory");

    {
        const float linv = 1.f / lB;
        const size_t obase = (bSEQ + qrowB) * HID + hoff + prow;
#pragma unroll
        for (int nt = 0; nt < 4; nt++) {
            ushort4 ov;
            ov.x = f2bf(oaB[nt][0] * linv);
            ov.y = f2bf(oaB[nt][1] * linv);
            ov.z = f2bf(oaB[nt][2] * linv);
            ov.w = f2bf(oaB[nt][3] * linv);
            *(ushort4*)&Op[obase + nt * 16] = ov;
        }
    }
    {
        const float linv = 1.f / lA;
        const size_t obase = (bSEQ + qrowA) * HID + hoff + prow;
#pragma unroll
        for (int nt = 0; nt < 4; nt++) {
            ushort4 ov;
            ov.x = f2bf(oaA[nt][0] * linv);
            ov.y = f2bf(oaA[nt][1] * linv);
            ov.z = f2bf(oaA[nt][2] * linv);
            ov.w = f2bf(oaA[nt][3] * linv);
            *(ushort4*)&Op[obase + nt * 16] = ov;
        }
    }
}

// ---------------------------------------------------------------------------
extern "C" void kernel_launch(void* const* d_in, const int* in_sizes, int n_in,
                              void* d_out, int out_size, void* d_ws, size_t ws_size,
                              hipStream_t stream) {
    const float* query = (const float*)d_in[0];
    const float* key   = (const float*)d_in[1];
    const float* value = (const float*)d_in[2];
    const float* mask  = (const float*)d_in[3];
    const float* Wq    = (const float*)d_in[4];
    const float* bq    = (const float*)d_in[5];
    const float* Wk    = (const float*)d_in[6];
    const float* bk    = (const float*)d_in[7];
    const float* Wv    = (const float*)d_in[8];
    const float* bv    = (const float*)d_in[9];
    const float* Wo    = (const float*)d_in[10];
    const float* bo    = (const float*)d_in[11];

    // workspace (bf16): 7 activation-size buffers + 4 weight buffers ≈ 125.5 MB
    const size_t eA = (size_t)MTOT * HID;
    const size_t eW = (size_t)HID * HID;
    ushort_t* qb  = (ushort_t*)d_ws;
    ushort_t* kb  = qb  + eA;
    ushort_t* vb  = kb  + eA;
    ushort_t* Qp  = vb  + eA;
    ushort_t* Kp  = Qp  + eA;
    ushort_t* Vtb = Kp  + eA;   // [H, B*S]
    ushort_t* Op  = Vtb + eA;
    ushort_t* wqb = Op  + eA;   // wqb,wkb,wvb,wob contiguous
    ushort_t* wkb = wqb + eW;
    ushort_t* wvb = wkb + eW;
    ushort_t* wob = wvb + eW;

    // fused casts: 2 launches (dests contiguous; seg math is pow-2)
    cast3_act<<<3 * N4A / 256, 256, 0, stream>>>(query, key, value, qb);
    cast4_w  <<<4 * N4W / 256, 256, 0, stream>>>(Wq, Wk, Wv, Wo, wqb);

    // fused QKV projections: 1536 blocks -> 4 blocks/CU co-residency
    qkv_gemm<<<dim3(512, 1, 3), 256, 0, stream>>>(
        qb, kb, wvb, wqb, wkb, vb, bq, bk, bv, Qp, Kp, Vtb);

    // flash attention: 1024 blocks, 4 waves each, XCD-local (b,h)
    attn_mfma<<<(BATCH * NH * 64) / 4, 256, 0, stream>>>(Qp, Kp, Vtb, mask, Op);

    // O-projection (fp32 out)
    dim3 gg(HID / 128, MTOT / 128);   // (8, 64)
    gemm_o<<<gg, 256, 0, stream>>>(Op, wob, bo, (float*)d_out, MTOT, HID, HID);
}

// Round 6
// 394.761 us; speedup vs baseline: 2.3545x; 1.0087x over previous
//
#include <hip/hip_runtime.h>
#include <hip/hip_bf16.h>
#include <math.h>

// Problem constants: B=4, S=2048, H=1024, nh=16, dh=64.
#define BATCH 4
#define SEQ   2048
#define HID   1024
#define NH    16
#define DH    64
#define MTOT  (BATCH * SEQ)   // 8192
#define FILLV (-1e13f)
#define N4A   (MTOT * HID / 4)   // 2^21 float4-groups per activation buffer
#define N4W   (HID * HID / 4)    // 2^18 per weight buffer

typedef unsigned short ushort_t;
typedef short bf16x8 __attribute__((ext_vector_type(8)));
typedef float f32x4  __attribute__((ext_vector_type(4)));

__device__ __forceinline__ float bf2f(ushort_t u) {
    return __uint_as_float(((unsigned int)u) << 16);
}
__device__ __forceinline__ ushort_t f2bf(float f) {
    union { __hip_bfloat16 h; ushort_t u; } cv;
    cv.h = __float2bfloat16(f);
    return cv.u;
}

// async global->LDS, 16B per lane; LDS dest = wave-uniform base + lane*16
__device__ __forceinline__ void gload16(const void* g, void* l) {
    __builtin_amdgcn_global_load_lds(
        (const __attribute__((address_space(1))) unsigned int*)g,
        (__attribute__((address_space(3))) unsigned int*)l, 16, 0, 0);
}

__device__ __forceinline__ ushort4 cvt4(const float4 v) {
    ushort4 o;
    o.x = f2bf(v.x); o.y = f2bf(v.y); o.z = f2bf(v.z); o.w = f2bf(v.w);
    return o;
}

// ---------------------------------------------------------------------------
// fused fp32->bf16 casts: 3 activation buffers -> contiguous dst (qb,kb,vb)
// ---------------------------------------------------------------------------
__global__ __launch_bounds__(256) void cast3_act(
    const float* __restrict__ s0, const float* __restrict__ s1,
    const float* __restrict__ s2, ushort_t* __restrict__ dst)
{
    const int i   = blockIdx.x * 256 + threadIdx.x;      // < 3*N4A
    const int seg = i >> 21;                             // block-uniform
    const int off = i & (N4A - 1);
    const float* s = (seg == 0) ? s0 : (seg == 1) ? s1 : s2;
    ((ushort4*)dst)[i] = cvt4(((const float4*)s)[off]);
}

// 4 weight buffers -> contiguous dst (wqb,wkb,wvb,wob)
__global__ __launch_bounds__(256) void cast4_w(
    const float* __restrict__ s0, const float* __restrict__ s1,
    const float* __restrict__ s2, const float* __restrict__ s3,
    ushort_t* __restrict__ dst)
{
    const int i   = blockIdx.x * 256 + threadIdx.x;      // < 4*N4W
    const int seg = i >> 18;
    const int off = i & (N4W - 1);
    const float* s = (seg == 0) ? s0 : (seg == 1) ? s1 : (seg == 2) ? s2 : s3;
    ((ushort4*)dst)[i] = cvt4(((const float4*)s)[off]);
}

// ---------------------------------------------------------------------------
// FUSED QKV-projection GEMM (1536 blocks, z selects the GEMM).
// ROUND-6: canonical single-barrier 2-phase K-loop (T3 minimum recipe):
//   iter: { STAGE(kt+1 -> buf^1); ds_read buf; MFMA; vmcnt(0); s_barrier; }
// The old loop had TWO barriers/iter (top-wait + end overwrite-guard). With
// STAGE issued before the reads and the single barrier at the END, the
// overwrite hazard is gone (a wave's LDS reads complete before it reaches
// the end barrier - consumed by MFMA under compiler lgkm waits - and the
// next STAGE into that buffer is issued only after the barrier). The
// vmcnt(0) drain is covered by 5-6 co-resident blocks/CU (m114 overlap).
// ---------------------------------------------------------------------------
__global__ __launch_bounds__(256) void qkv_gemm(
    const ushort_t* __restrict__ A0, const ushort_t* __restrict__ A1,
    const ushort_t* __restrict__ A2,
    const ushort_t* __restrict__ W0, const ushort_t* __restrict__ W1,
    const ushort_t* __restrict__ W2,
    const float* __restrict__ b0, const float* __restrict__ b1,
    const float* __restrict__ b2,
    ushort_t* __restrict__ Y0, ushort_t* __restrict__ Y1,
    ushort_t* __restrict__ Y2)
{
    __shared__ ushort_t As[2][4096];
    __shared__ ushort_t Bs[2][4096];

    const int z = blockIdx.z;
    const ushort_t* A    = (z == 0) ? A0 : (z == 1) ? A1 : A2;
    const ushort_t* W    = (z == 0) ? W0 : (z == 1) ? W1 : W2;
    const float*    bias = (z == 0) ? b0 : (z == 1) ? b1 : b2;
    ushort_t*       Y    = (z == 0) ? Y0 : (z == 1) ? Y1 : Y2;
    const int  Nz   = (z == 2) ? MTOT : HID;
    const int  gx   = Nz >> 7;            // n-blocks: 64 or 8
    const bool brow = (z == 2);

    const int tid  = threadIdx.x;
    const int lane = tid & 63;
    const int wave = tid >> 6;
    const int wm   = wave & 1;
    const int wn   = wave >> 1;

    // XCD-chunked bijective swizzle within this z-slice (512 blocks, 64/XCD).
    const int flat = blockIdx.x;
    const int fl2  = (flat & 7) * 64 + (flat >> 3);
    const int bx   = fl2 % gx;
    const int by   = fl2 / gx;

    const int m0   = by * 128;
    const int n0   = bx * 128;
    const int lr   = lane & 15;
    const int lk   = (lane >> 4) * 8;

    f32x4 acc[4][4];
#pragma unroll
    for (int i = 0; i < 4; i++)
#pragma unroll
        for (int j = 0; j < 4; j++) acc[i][j] = (f32x4){0.f, 0.f, 0.f, 0.f};

    // stage K-chunk kk into buffer d (4 VMEM per thread); K = HID = 1024
    auto STAGE = [&](int kk, int d) {
        const ushort_t* a = A + (size_t)(m0 + wave * 32 + lr) * HID + kk + lk;
        const ushort_t* w = W + (size_t)(n0 + wave * 32 + lr) * HID + kk + lk;
        ushort_t* al = &As[d][wave * 1024];
        ushort_t* bl = &Bs[d][wave * 1024];
        gload16(a,            al);
        gload16(a + 16 * HID, al + 512);
        gload16(w,            bl);
        gload16(w + 16 * HID, bl + 512);
    };

    const int nk = HID >> 5;   // 32
    STAGE(0, 0);
    asm volatile("s_waitcnt vmcnt(0)" ::: "memory");
    __builtin_amdgcn_s_barrier();

    for (int kt = 0; kt < nk; ++kt) {
        const int d = kt & 1;
        if (kt + 1 < nk) STAGE((kt + 1) << 5, d ^ 1);   // issue-early
        __builtin_amdgcn_sched_barrier(0);

        bf16x8 af[4], bf[4];
#pragma unroll
        for (int i = 0; i < 4; i++)
            af[i] = *(const bf16x8*)&As[d][(wm * 4 + i) * 512 + lane * 8];
#pragma unroll
        for (int j = 0; j < 4; j++)
            bf[j] = *(const bf16x8*)&Bs[d][(wn * 4 + j) * 512 + lane * 8];
#pragma unroll
        for (int i = 0; i < 4; i++)
#pragma unroll
            for (int j = 0; j < 4; j++)
                acc[i][j] = __builtin_amdgcn_mfma_f32_16x16x32_bf16(
                    af[i], bf[j], acc[i][j], 0, 0, 0);

        // single end-of-iter sync: next-tile stage complete + all waves done
        // reading buf d before the NEXT iteration's STAGE overwrites buf d^1.
        __builtin_amdgcn_sched_barrier(0);
        asm volatile("s_waitcnt vmcnt(0)" ::: "memory");
        __builtin_amdgcn_s_barrier();
    }

    const int orow = (lane >> 4) * 4;
    const int ocol = lane & 15;
#pragma unroll
    for (int i = 0; i < 4; i++) {
#pragma unroll
        for (int j = 0; j < 4; j++) {
            const int col = n0 + wn * 64 + j * 16 + ocol;
#pragma unroll
            for (int r = 0; r < 4; r++) {
                const int row = m0 + wm * 64 + i * 16 + orow + r;
                const float bvv = brow ? bias[row] : bias[col];
                Y[(size_t)row * Nz + col] = f2bf(acc[i][j][r] + bvv);
            }
        }
    }
}

// ---------------------------------------------------------------------------
// O-projection GEMM (fp32 out) - same single-barrier 2-phase loop.
// ---------------------------------------------------------------------------
__global__ __launch_bounds__(256) void gemm_o(
    const ushort_t* __restrict__ A,   // [M,K] bf16
    const ushort_t* __restrict__ W,   // [N,K] bf16
    const float*    __restrict__ bias,
    float* __restrict__ Yv,           // [M,N] fp32
    int M, int N, int K)
{
    __shared__ ushort_t As[2][4096];
    __shared__ ushort_t Bs[2][4096];

    const int tid  = threadIdx.x;
    const int lane = tid & 63;
    const int wave = tid >> 6;
    const int wm   = wave & 1;
    const int wn   = wave >> 1;

    const int flat = blockIdx.y * gridDim.x + blockIdx.x;
    const int cpx  = (gridDim.x * gridDim.y) >> 3;
    const int fl2  = (flat & 7) * cpx + (flat >> 3);
    const int bx   = fl2 % gridDim.x;
    const int by   = fl2 / gridDim.x;

    const int m0   = by * 128;
    const int n0   = bx * 128;
    const int lr   = lane & 15;
    const int lk   = (lane >> 4) * 8;

    f32x4 acc[4][4];
#pragma unroll
    for (int i = 0; i < 4; i++)
#pragma unroll
        for (int j = 0; j < 4; j++) acc[i][j] = (f32x4){0.f, 0.f, 0.f, 0.f};

    auto STAGE = [&](int kk, int d) {
        const ushort_t* a = A + (size_t)(m0 + wave * 32 + lr) * K + kk + lk;
        const ushort_t* w = W + (size_t)(n0 + wave * 32 + lr) * K + kk + lk;
        ushort_t* al = &As[d][wave * 1024];
        ushort_t* bl = &Bs[d][wave * 1024];
        gload16(a,                  al);
        gload16(a + (size_t)16 * K, al + 512);
        gload16(w,                  bl);
        gload16(w + (size_t)16 * K, bl + 512);
    };

    const int nk = K >> 5;
    STAGE(0, 0);
    asm volatile("s_waitcnt vmcnt(0)" ::: "memory");
    __builtin_amdgcn_s_barrier();

    for (int kt = 0; kt < nk; ++kt) {
        const int d = kt & 1;
        if (kt + 1 < nk) STAGE((kt + 1) << 5, d ^ 1);
        __builtin_amdgcn_sched_barrier(0);

        bf16x8 af[4], bf[4];
#pragma unroll
        for (int i = 0; i < 4; i++)
            af[i] = *(const bf16x8*)&As[d][(wm * 4 + i) * 512 + lane * 8];
#pragma unroll
        for (int j = 0; j < 4; j++)
            bf[j] = *(const bf16x8*)&Bs[d][(wn * 4 + j) * 512 + lane * 8];
#pragma unroll
        for (int i = 0; i < 4; i++)
#pragma unroll
            for (int j = 0; j < 4; j++)
                acc[i][j] = __builtin_amdgcn_mfma_f32_16x16x32_bf16(
                    af[i], bf[j], acc[i][j], 0, 0, 0);

        __builtin_amdgcn_sched_barrier(0);
        asm volatile("s_waitcnt vmcnt(0)" ::: "memory");
        __builtin_amdgcn_s_barrier();
    }

    const int orow = (lane >> 4) * 4;
    const int ocol = lane & 15;
#pragma unroll
    for (int i = 0; i < 4; i++) {
#pragma unroll
        for (int j = 0; j < 4; j++) {
            const int col = n0 + wn * 64 + j * 16 + ocol;
#pragma unroll
            for (int r = 0; r < 4; r++) {
                const int row = m0 + wm * 64 + i * 16 + orow + r;
                Yv[(size_t)row * N + col] = acc[i][j][r] + bias[col];
            }
        }
    }
}

// ---------------------------------------------------------------------------
// MFMA flash attention v4: same verified structure as round 3/5 but with the
// canonical single-barrier 2-phase K/V loop (one vmcnt(0)+s_barrier per
// tile, at the END; STAGE issued at the top). The drain is covered by the
// long compute phase (2 QK clusters + softmax + PV) plus 3 blocks/CU.
// ---------------------------------------------------------------------------
__global__ __launch_bounds__(256, 2) void attn_mfma(
    const ushort_t* __restrict__ Qp,   // [B*S, H]
    const ushort_t* __restrict__ Kp,   // [B*S, H]
    const ushort_t* __restrict__ Vt,   // [H, B*S]
    const float*    __restrict__ mask, // [B, S] over key positions
    ushort_t* __restrict__ Op)         // [B*S, H]
{
    __shared__ ushort_t Kl[2][4096];     // [buf][64 rows x 64 elem] 8KB each
    __shared__ ushort_t Vl[2][4096];
    __shared__ ushort_t PlA[4][16 * 72]; // per-wave P^T slabs
    __shared__ ushort_t PlB[4][16 * 72];

    const int tid  = threadIdx.x;
    const int lane = tid & 63;
    const int wave = tid >> 6;
    const int li   = lane & 15;   // frag idx | C/D col (= q index)
    const int lq   = lane >> 4;   // quad
    const int blk  = blockIdx.x;
    const int xcd = blk & 7;
    const int jj  = blk >> 3;            // 0..127
    const int bh  = xcd * 8 + (jj & 7);  // 0..63
    const int pp  = jj >> 3;             // 0..15
    const int pr  = pp * 4 + wave;       // 0..63
    const int h   = bh & (NH - 1);
    const int b   = bh >> 4;
    const int prow = lq * 4;

    const int q0a = pr * 16;             // tile A (jmaxA = pp)
    const int q0b = (127 - pr) * 16;     // tile B (jmaxB = 31-pp)
    const int qrowA = q0a + li;
    const int qrowB = q0b + li;
    const int jmaxB = 31 - pp;

    const size_t bSEQ = (size_t)b * SEQ;
    const int    hoff = h * DH;

    const int srow = tid >> 3;
    const int scs8 = ((tid & 7) ^ (srow & 7)) * 8;   // swizzled chunk * 8 elems

    const int fr0 = li * 64 + ((lq ^ (li & 7)) * 8);

    ushort_t* pwA = &PlA[wave][0];
    ushort_t* pwB = &PlB[wave][0];

    const float* mbase = mask + bSEQ + prow;   // padding mask, indexed by key

    const size_t qaA = (bSEQ + qrowA) * HID + hoff + lq * 8;
    const size_t qaB = (bSEQ + qrowB) * HID + hoff + lq * 8;
    const bf16x8 qfA0 = *(const bf16x8*)&Qp[qaA];
    const bf16x8 qfA1 = *(const bf16x8*)&Qp[qaA + 32];
    const bf16x8 qfB0 = *(const bf16x8*)&Qp[qaB];
    const bf16x8 qfB1 = *(const bf16x8*)&Qp[qaB + 32];

    f32x4 oaA[4], oaB[4];
#pragma unroll
    for (int nt = 0; nt < 4; nt++) {
        oaA[nt] = (f32x4){0.f, 0.f, 0.f, 0.f};
        oaB[nt] = (f32x4){0.f, 0.f, 0.f, 0.f};
    }
    float mA = -1e30f, lA = 0.f, mB = -1e30f, lB = 0.f;

    auto STAGE = [&](int js, int bs) {
        const size_t k0s = (size_t)js * 64;
        const ushort_t* kg = Kp + (bSEQ + k0s + srow) * HID + hoff + scs8;
        ushort_t* kl = &Kl[bs][wave * 512];
        gload16(kg, kl);
        gload16(kg + (size_t)32 * HID, kl + 2048);
        const ushort_t* vg = Vt + (size_t)(hoff + srow) * MTOT + bSEQ + k0s + scs8;
        ushort_t* vl = &Vl[bs][wave * 512];
        gload16(vg, vl);
        gload16(vg + (size_t)32 * MTOT, vl + 2048);
    };

    STAGE(0, 0);
    asm volatile("s_waitcnt vmcnt(0)" ::: "memory");
    __builtin_amdgcn_s_barrier();

    for (int j = 0; j <= jmaxB; ++j) {
        const int  k0  = j * 64;
        const int  bs  = j & 1;
        const bool doA = (j <= pp);          // block-uniform

        f32x4 mk[4];
#pragma unroll
        for (int nt = 0; nt < 4; nt++)
            mk[nt] = *(const f32x4*)&mbase[k0 + nt * 16];
        __builtin_amdgcn_sched_barrier(0);

        if (j < jmaxB) STAGE(j + 1, bs ^ 1);   // issue-early, consumed next iter
        __builtin_amdgcn_sched_barrier(0);

        bf16x8 kf[4][2];
#pragma unroll
        for (int nt = 0; nt < 4; nt++) {
            const int eo = nt * 1024 + fr0;
            kf[nt][0] = *(const bf16x8*)&Kl[bs][eo];
            kf[nt][1] = *(const bf16x8*)&Kl[bs][eo ^ 32];
        }

        f32x4 saA[4], saB[4];
        __builtin_amdgcn_s_setprio(1);
#pragma unroll
        for (int nt = 0; nt < 4; nt++) {
            f32x4 a = (f32x4){0.f, 0.f, 0.f, 0.f};
            a = __builtin_amdgcn_mfma_f32_16x16x32_bf16(kf[nt][0], qfB0, a, 0, 0, 0);
            a = __builtin_amdgcn_mfma_f32_16x16x32_bf16(kf[nt][1], qfB1, a, 0, 0, 0);
            saB[nt] = a;
        }
        if (doA) {
#pragma unroll
            for (int nt = 0; nt < 4; nt++) {
                f32x4 a = (f32x4){0.f, 0.f, 0.f, 0.f};
                a = __builtin_amdgcn_mfma_f32_16x16x32_bf16(kf[nt][0], qfA0, a, 0, 0, 0);
                a = __builtin_amdgcn_mfma_f32_16x16x32_bf16(kf[nt][1], qfA1, a, 0, 0, 0);
                saA[nt] = a;
            }
        }
        __builtin_amdgcn_s_setprio(0);

        float sB[4][4];
#pragma unroll
        for (int nt = 0; nt < 4; nt++)
#pragma unroll
            for (int r = 0; r < 4; r++) {
                const float v = saB[nt][r] * 0.125f;
                sB[nt][r] = (mk[nt][r] == 0.f) ? FILLV : v;
            }
        if (k0 + 63 > q0b) {
#pragma unroll
            for (int nt = 0; nt < 4; nt++)
#pragma unroll
                for (int r = 0; r < 4; r++) {
                    const int kpos = k0 + nt * 16 + prow + r;
                    sB[nt][r] = (kpos > qrowB) ? FILLV : sB[nt][r];
                }
        }
        float pmB = fmaxf(fmaxf(sB[0][0], sB[0][1]), fmaxf(sB[0][2], sB[0][3]));
#pragma unroll
        for (int nt = 1; nt < 4; nt++)
            pmB = fmaxf(pmB, fmaxf(fmaxf(sB[nt][0], sB[nt][1]),
                                   fmaxf(sB[nt][2], sB[nt][3])));
        pmB = fmaxf(pmB, __shfl_xor(pmB, 16));
        pmB = fmaxf(pmB, __shfl_xor(pmB, 32));
        const float mnB = fmaxf(mB, pmB);
        const float alB = __expf(mB - mnB);
        mB = mnB;
        float psB = 0.f;
#pragma unroll
        for (int nt = 0; nt < 4; nt++) {
            const float p0 = __expf(sB[nt][0] - mnB);
            const float p1 = __expf(sB[nt][1] - mnB);
            const float p2 = __expf(sB[nt][2] - mnB);
            const float p3 = __expf(sB[nt][3] - mnB);
            psB += (p0 + p1) + (p2 + p3);
            ushort4 pk;
            pk.x = f2bf(p0); pk.y = f2bf(p1); pk.z = f2bf(p2); pk.w = f2bf(p3);
            *(ushort4*)&pwB[li * 72 + nt * 16 + prow] = pk;
        }
        psB += __shfl_xor(psB, 16);
        psB += __shfl_xor(psB, 32);
        lB = lB * alB + psB;

        float alA = 1.f;
        if (doA) {
            float sA[4][4];
#pragma unroll
            for (int nt = 0; nt < 4; nt++)
#pragma unroll
                for (int r = 0; r < 4; r++) {
                    const float v = saA[nt][r] * 0.125f;
                    sA[nt][r] = (mk[nt][r] == 0.f) ? FILLV : v;
                }
            if (k0 + 63 > q0a) {
#pragma unroll
                for (int nt = 0; nt < 4; nt++)
#pragma unroll
                    for (int r = 0; r < 4; r++) {
                        const int kpos = k0 + nt * 16 + prow + r;
                        sA[nt][r] = (kpos > qrowA) ? FILLV : sA[nt][r];
                    }
            }
            float pmA = fmaxf(fmaxf(sA[0][0], sA[0][1]), fmaxf(sA[0][2], sA[0][3]));
#pragma unroll
            for (int nt = 1; nt < 4; nt++)
                pmA = fmaxf(pmA, fmaxf(fmaxf(sA[nt][0], sA[nt][1]),
                                       fmaxf(sA[nt][2], sA[nt][3])));
            pmA = fmaxf(pmA, __shfl_xor(pmA, 16));
            pmA = fmaxf(pmA, __shfl_xor(pmA, 32));
            const float mnA = fmaxf(mA, pmA);
            alA = __expf(mA - mnA);
            mA = mnA;
            float psA = 0.f;
#pragma unroll
            for (int nt = 0; nt < 4; nt++) {
                const float p0 = __expf(sA[nt][0] - mnA);
                const float p1 = __expf(sA[nt][1] - mnA);
                const float p2 = __expf(sA[nt][2] - mnA);
                const float p3 = __expf(sA[nt][3] - mnA);
                psA += (p0 + p1) + (p2 + p3);
                ushort4 pk;
                pk.x = f2bf(p0); pk.y = f2bf(p1); pk.z = f2bf(p2); pk.w = f2bf(p3);
                *(ushort4*)&pwA[li * 72 + nt * 16 + prow] = pk;
            }
            psA += __shfl_xor(psA, 16);
            psA += __shfl_xor(psA, 32);
            lA = lA * alA + psA;
        }

        const bf16x8 pfB0 = *(const bf16x8*)&pwB[li * 72 + lq * 8];
        const bf16x8 pfB1 = *(const bf16x8*)&pwB[li * 72 + 32 + lq * 8];
        bf16x8 vf[4][2];
#pragma unroll
        for (int nt = 0; nt < 4; nt++) {
            const int eo = nt * 1024 + fr0;
            vf[nt][0] = *(const bf16x8*)&Vl[bs][eo];
            vf[nt][1] = *(const bf16x8*)&Vl[bs][eo ^ 32];
        }

        __builtin_amdgcn_s_setprio(1);
#pragma unroll
        for (int nt = 0; nt < 4; nt++) {
            f32x4 o = oaB[nt];
#pragma unroll
            for (int r = 0; r < 4; r++) o[r] *= alB;
            o = __builtin_amdgcn_mfma_f32_16x16x32_bf16(vf[nt][0], pfB0, o, 0, 0, 0);
            o = __builtin_amdgcn_mfma_f32_16x16x32_bf16(vf[nt][1], pfB1, o, 0, 0, 0);
            oaB[nt] = o;
        }
        __builtin_amdgcn_s_setprio(0);
        if (doA) {
            const bf16x8 pfA0 = *(const bf16x8*)&pwA[li * 72 + lq * 8];
            const bf16x8 pfA1 = *(const bf16x8*)&pwA[li * 72 + 32 + lq * 8];
            __builtin_amdgcn_s_setprio(1);
#pragma unroll
            for (int nt = 0; nt < 4; nt++) {
                f32x4 o = oaA[nt];
#pragma unroll
                for (int r = 0; r < 4; r++) o[r] *= alA;
                o = __builtin_amdgcn_mfma_f32_16x16x32_bf16(vf[nt][0], pfA0, o, 0, 0, 0);
                o = __builtin_amdgcn_mfma_f32_16x16x32_bf16(vf[nt][1], pfA1, o, 0, 0, 0);
                oaA[nt] = o;
            }
            __builtin_amdgcn_s_setprio(0);
        }

        // single end-of-iter sync: next tile staged + all reads of buf bs done
        __builtin_amdgcn_sched_barrier(0);
        asm volatile("s_waitcnt vmcnt(0)" ::: "memory");
        __builtin_amdgcn_s_barrier();
    }

    {
        const float linv = 1.f / lB;
        const size_t obase = (bSEQ + qrowB) * HID + hoff + prow;
#pragma unroll
        for (int nt = 0; nt < 4; nt++) {
            ushort4 ov;
            ov.x = f2bf(oaB[nt][0] * linv);
            ov.y = f2bf(oaB[nt][1] * linv);
            ov.z = f2bf(oaB[nt][2] * linv);
            ov.w = f2bf(oaB[nt][3] * linv);
            *(ushort4*)&Op[obase + nt * 16] = ov;
        }
    }
    {
        const float linv = 1.f / lA;
        const size_t obase = (bSEQ + qrowA) * HID + hoff + prow;
#pragma unroll
        for (int nt = 0; nt < 4; nt++) {
            ushort4 ov;
            ov.x = f2bf(oaA[nt][0] * linv);
            ov.y = f2bf(oaA[nt][1] * linv);
            ov.z = f2bf(oaA[nt][2] * linv);
            ov.w = f2bf(oaA[nt][3] * linv);
            *(ushort4*)&Op[obase + nt * 16] = ov;
        }
    }
}

// ---------------------------------------------------------------------------
extern "C" void kernel_launch(void* const* d_in, const int* in_sizes, int n_in,
                              void* d_out, int out_size, void* d_ws, size_t ws_size,
                              hipStream_t stream) {
    const float* query = (const float*)d_in[0];
    const float* key   = (const float*)d_in[1];
    const float* value = (const float*)d_in[2];
    const float* mask  = (const float*)d_in[3];
    const float* Wq    = (const float*)d_in[4];
    const float* bq    = (const float*)d_in[5];
    const float* Wk    = (const float*)d_in[6];
    const float* bk    = (const float*)d_in[7];
    const float* Wv    = (const float*)d_in[8];
    const float* bv    = (const float*)d_in[9];
    const float* Wo    = (const float*)d_in[10];
    const float* bo    = (const float*)d_in[11];

    // workspace (bf16): 7 activation-size buffers + 4 weight buffers ≈ 125.5 MB
    const size_t eA = (size_t)MTOT * HID;
    const size_t eW = (size_t)HID * HID;
    ushort_t* qb  = (ushort_t*)d_ws;
    ushort_t* kb  = qb  + eA;
    ushort_t* vb  = kb  + eA;
    ushort_t* Qp  = vb  + eA;
    ushort_t* Kp  = Qp  + eA;
    ushort_t* Vtb = Kp  + eA;   // [H, B*S]
    ushort_t* Op  = Vtb + eA;
    ushort_t* wqb = Op  + eA;   // wqb,wkb,wvb,wob contiguous
    ushort_t* wkb = wqb + eW;
    ushort_t* wvb = wkb + eW;
    ushort_t* wob = wvb + eW;

    // fused casts: 2 launches (dests contiguous; seg math is pow-2)
    cast3_act<<<3 * N4A / 256, 256, 0, stream>>>(query, key, value, qb);
    cast4_w  <<<4 * N4W / 256, 256, 0, stream>>>(Wq, Wk, Wv, Wo, wqb);

    // fused QKV projections: 1536 blocks -> 5-6 blocks/CU co-residency
    qkv_gemm<<<dim3(512, 1, 3), 256, 0, stream>>>(
        qb, kb, wvb, wqb, wkb, vb, bq, bk, bv, Qp, Kp, Vtb);

    // flash attention: 1024 blocks, 4 waves each, XCD-local (b,h)
    attn_mfma<<<(BATCH * NH * 64) / 4, 256, 0, stream>>>(Qp, Kp, Vtb, mask, Op);

    // O-projection (fp32 out)
    dim3 gg(HID / 128, MTOT / 128);   // (8, 64)
    gemm_o<<<gg, 256, 0, stream>>>(Op, wob, bo, (float*)d_out, MTOT, HID, HID);
}

// Round 7
// 386.848 us; speedup vs baseline: 2.4027x; 1.0205x over previous
//
#include <hip/hip_runtime.h>
#include <hip/hip_bf16.h>
#include <math.h>

// Problem constants: B=4, S=2048, H=1024, nh=16, dh=64.
#define BATCH 4
#define SEQ   2048
#define HID   1024
#define NH    16
#define DH    64
#define MTOT  (BATCH * SEQ)   // 8192
#define FILLV (-1e13f)
#define N4A   (MTOT * HID / 4)   // 2^21 float4-groups per activation buffer
#define N4W   (HID * HID / 4)    // 2^18 per weight buffer

typedef unsigned short ushort_t;
typedef short bf16x8 __attribute__((ext_vector_type(8)));
typedef float f32x4  __attribute__((ext_vector_type(4)));

__device__ __forceinline__ float bf2f(ushort_t u) {
    return __uint_as_float(((unsigned int)u) << 16);
}
__device__ __forceinline__ ushort_t f2bf(float f) {
    union { __hip_bfloat16 h; ushort_t u; } cv;
    cv.h = __float2bfloat16(f);
    return cv.u;
}

// async global->LDS, 16B per lane; LDS dest = wave-uniform base + lane*16
__device__ __forceinline__ void gload16(const void* g, void* l) {
    __builtin_amdgcn_global_load_lds(
        (const __attribute__((address_space(1))) unsigned int*)g,
        (__attribute__((address_space(3))) unsigned int*)l, 16, 0, 0);
}

__device__ __forceinline__ ushort4 cvt4(const float4 v) {
    ushort4 o;
    o.x = f2bf(v.x); o.y = f2bf(v.y); o.z = f2bf(v.z); o.w = f2bf(v.w);
    return o;
}

// ---------------------------------------------------------------------------
// fused fp32->bf16 casts
// ---------------------------------------------------------------------------
__global__ __launch_bounds__(256) void cast3_act(
    const float* __restrict__ s0, const float* __restrict__ s1,
    const float* __restrict__ s2, ushort_t* __restrict__ dst)
{
    const int i   = blockIdx.x * 256 + threadIdx.x;      // < 3*N4A
    const int seg = i >> 21;                             // block-uniform
    const int off = i & (N4A - 1);
    const float* s = (seg == 0) ? s0 : (seg == 1) ? s1 : s2;
    ((ushort4*)dst)[i] = cvt4(((const float4*)s)[off]);
}

__global__ __launch_bounds__(256) void cast4_w(
    const float* __restrict__ s0, const float* __restrict__ s1,
    const float* __restrict__ s2, const float* __restrict__ s3,
    ushort_t* __restrict__ dst)
{
    const int i   = blockIdx.x * 256 + threadIdx.x;      // < 4*N4W
    const int seg = i >> 18;
    const int off = i & (N4W - 1);
    const float* s = (seg == 0) ? s0 : (seg == 1) ? s1 : (seg == 2) ? s2 : s3;
    ((ushort4*)dst)[i] = cvt4(((const float4*)s)[off]);
}

// ---------------------------------------------------------------------------
// FUSED QKV-projection GEMM (1536 blocks, z selects the GEMM).
// ROUND-7: TRIPLE-buffered LDS, 2-iteration prefetch span (T4 proper).
// Rounds 5/6 A/B-isolated that barrier count is NOT the cost (identical
// 120.5 us with 2 vs 1 barriers/iter) - both had only ONE iteration of
// load-latency coverage. Pipe accounting: wall 1500 cyc/block-iter vs
// LDS 384 + MFMA 282 -> ~40% correlated idle on the stage wait.
// New cadence per iter:
//   vmcnt(4)            // stage(t) landed; stage(t+1) stays in flight
//   s_barrier           // all waves' stage(t) visible + t-1 reads done
//   STAGE(t+2)->buf[(t+2)%3]   // that buf last read in iter t-1: safe
//   ds_read buf[t%3]; 16x MFMA  // no trailing barrier needed
// Stage(t) is issued 2 iterations before use -> ~1500+ cyc coverage > HBM.
// ---------------------------------------------------------------------------
__global__ __launch_bounds__(256) void qkv_gemm(
    const ushort_t* __restrict__ A0, const ushort_t* __restrict__ A1,
    const ushort_t* __restrict__ A2,
    const ushort_t* __restrict__ W0, const ushort_t* __restrict__ W1,
    const ushort_t* __restrict__ W2,
    const float* __restrict__ b0, const float* __restrict__ b1,
    const float* __restrict__ b2,
    ushort_t* __restrict__ Y0, ushort_t* __restrict__ Y1,
    ushort_t* __restrict__ Y2)
{
    __shared__ ushort_t As[3][4096];
    __shared__ ushort_t Bs[3][4096];

    const int z = blockIdx.z;
    const ushort_t* A    = (z == 0) ? A0 : (z == 1) ? A1 : A2;
    const ushort_t* W    = (z == 0) ? W0 : (z == 1) ? W1 : W2;
    const float*    bias = (z == 0) ? b0 : (z == 1) ? b1 : b2;
    ushort_t*       Y    = (z == 0) ? Y0 : (z == 1) ? Y1 : Y2;
    const int  Nz   = (z == 2) ? MTOT : HID;
    const int  gx   = Nz >> 7;            // n-blocks: 64 or 8
    const bool brow = (z == 2);

    const int tid  = threadIdx.x;
    const int lane = tid & 63;
    const int wave = tid >> 6;
    const int wm   = wave & 1;
    const int wn   = wave >> 1;

    // XCD-chunked bijective swizzle within this z-slice (512 blocks, 64/XCD).
    const int flat = blockIdx.x;
    const int fl2  = (flat & 7) * 64 + (flat >> 3);
    const int bx   = fl2 % gx;
    const int by   = fl2 / gx;

    const int m0   = by * 128;
    const int n0   = bx * 128;
    const int lr   = lane & 15;
    const int lk   = (lane >> 4) * 8;

    f32x4 acc[4][4];
#pragma unroll
    for (int i = 0; i < 4; i++)
#pragma unroll
        for (int j = 0; j < 4; j++) acc[i][j] = (f32x4){0.f, 0.f, 0.f, 0.f};

    // stage K-chunk kk into buffer d (4 VMEM per thread); K = HID = 1024
    auto STAGE = [&](int kk, int d) {
        const ushort_t* a = A + (size_t)(m0 + wave * 32 + lr) * HID + kk + lk;
        const ushort_t* w = W + (size_t)(n0 + wave * 32 + lr) * HID + kk + lk;
        ushort_t* al = &As[d][wave * 1024];
        ushort_t* bl = &Bs[d][wave * 1024];
        gload16(a,            al);
        gload16(a + 16 * HID, al + 512);
        gload16(w,            bl);
        gload16(w + 16 * HID, bl + 512);
    };

    const int nk = HID >> 5;   // 32
    STAGE(0, 0);
    if (nk > 1) STAGE(32, 1);

    for (int kt = 0; kt < nk; ++kt) {
        const int d = kt % 3;
        if (kt + 1 < nk) {
            asm volatile("s_waitcnt vmcnt(4)" ::: "memory");   // stage(kt) done
        } else {
            asm volatile("s_waitcnt vmcnt(0)" ::: "memory");
        }
        __builtin_amdgcn_s_barrier();
        __builtin_amdgcn_sched_barrier(0);
        if (kt + 2 < nk) STAGE((kt + 2) << 5, (kt + 2) % 3);
        __builtin_amdgcn_sched_barrier(0);

        bf16x8 af[4], bf[4];
#pragma unroll
        for (int i = 0; i < 4; i++)
            af[i] = *(const bf16x8*)&As[d][(wm * 4 + i) * 512 + lane * 8];
#pragma unroll
        for (int j = 0; j < 4; j++)
            bf[j] = *(const bf16x8*)&Bs[d][(wn * 4 + j) * 512 + lane * 8];
#pragma unroll
        for (int i = 0; i < 4; i++)
#pragma unroll
            for (int j = 0; j < 4; j++)
                acc[i][j] = __builtin_amdgcn_mfma_f32_16x16x32_bf16(
                    af[i], bf[j], acc[i][j], 0, 0, 0);
        // no trailing barrier: next iter's top barrier orders buf overwrite
    }

    const int orow = (lane >> 4) * 4;
    const int ocol = lane & 15;
#pragma unroll
    for (int i = 0; i < 4; i++) {
#pragma unroll
        for (int j = 0; j < 4; j++) {
            const int col = n0 + wn * 64 + j * 16 + ocol;
#pragma unroll
            for (int r = 0; r < 4; r++) {
                const int row = m0 + wm * 64 + i * 16 + orow + r;
                const float bvv = brow ? bias[row] : bias[col];
                Y[(size_t)row * Nz + col] = f2bf(acc[i][j][r] + bvv);
            }
        }
    }
}

// ---------------------------------------------------------------------------
// O-projection GEMM (fp32 out) - same triple-buffered 2-deep loop.
// ---------------------------------------------------------------------------
__global__ __launch_bounds__(256) void gemm_o(
    const ushort_t* __restrict__ A,   // [M,K] bf16
    const ushort_t* __restrict__ W,   // [N,K] bf16
    const float*    __restrict__ bias,
    float* __restrict__ Yv,           // [M,N] fp32
    int M, int N, int K)
{
    __shared__ ushort_t As[3][4096];
    __shared__ ushort_t Bs[3][4096];

    const int tid  = threadIdx.x;
    const int lane = tid & 63;
    const int wave = tid >> 6;
    const int wm   = wave & 1;
    const int wn   = wave >> 1;

    const int flat = blockIdx.y * gridDim.x + blockIdx.x;
    const int cpx  = (gridDim.x * gridDim.y) >> 3;
    const int fl2  = (flat & 7) * cpx + (flat >> 3);
    const int bx   = fl2 % gridDim.x;
    const int by   = fl2 / gridDim.x;

    const int m0   = by * 128;
    const int n0   = bx * 128;
    const int lr   = lane & 15;
    const int lk   = (lane >> 4) * 8;

    f32x4 acc[4][4];
#pragma unroll
    for (int i = 0; i < 4; i++)
#pragma unroll
        for (int j = 0; j < 4; j++) acc[i][j] = (f32x4){0.f, 0.f, 0.f, 0.f};

    auto STAGE = [&](int kk, int d) {
        const ushort_t* a = A + (size_t)(m0 + wave * 32 + lr) * K + kk + lk;
        const ushort_t* w = W + (size_t)(n0 + wave * 32 + lr) * K + kk + lk;
        ushort_t* al = &As[d][wave * 1024];
        ushort_t* bl = &Bs[d][wave * 1024];
        gload16(a,                  al);
        gload16(a + (size_t)16 * K, al + 512);
        gload16(w,                  bl);
        gload16(w + (size_t)16 * K, bl + 512);
    };

    const int nk = K >> 5;
    STAGE(0, 0);
    if (nk > 1) STAGE(32, 1);

    for (int kt = 0; kt < nk; ++kt) {
        const int d = kt % 3;
        if (kt + 1 < nk) {
            asm volatile("s_waitcnt vmcnt(4)" ::: "memory");
        } else {
            asm volatile("s_waitcnt vmcnt(0)" ::: "memory");
        }
        __builtin_amdgcn_s_barrier();
        __builtin_amdgcn_sched_barrier(0);
        if (kt + 2 < nk) STAGE((kt + 2) << 5, (kt + 2) % 3);
        __builtin_amdgcn_sched_barrier(0);

        bf16x8 af[4], bf[4];
#pragma unroll
        for (int i = 0; i < 4; i++)
            af[i] = *(const bf16x8*)&As[d][(wm * 4 + i) * 512 + lane * 8];
#pragma unroll
        for (int j = 0; j < 4; j++)
            bf[j] = *(const bf16x8*)&Bs[d][(wn * 4 + j) * 512 + lane * 8];
#pragma unroll
        for (int i = 0; i < 4; i++)
#pragma unroll
            for (int j = 0; j < 4; j++)
                acc[i][j] = __builtin_amdgcn_mfma_f32_16x16x32_bf16(
                    af[i], bf[j], acc[i][j], 0, 0, 0);
    }

    const int orow = (lane >> 4) * 4;
    const int ocol = lane & 15;
#pragma unroll
    for (int i = 0; i < 4; i++) {
#pragma unroll
        for (int j = 0; j < 4; j++) {
            const int col = n0 + wn * 64 + j * 16 + ocol;
#pragma unroll
            for (int r = 0; r < 4; r++) {
                const int row = m0 + wm * 64 + i * 16 + orow + r;
                Yv[(size_t)row * N + col] = acc[i][j][r] + bias[col];
            }
        }
    }
}

// ---------------------------------------------------------------------------
// MFMA flash attention v4 (verified rounds 3-6, ~107 us). UNCHANGED.
// ---------------------------------------------------------------------------
__global__ __launch_bounds__(256, 2) void attn_mfma(
    const ushort_t* __restrict__ Qp,   // [B*S, H]
    const ushort_t* __restrict__ Kp,   // [B*S, H]
    const ushort_t* __restrict__ Vt,   // [H, B*S]
    const float*    __restrict__ mask, // [B, S] over key positions
    ushort_t* __restrict__ Op)         // [B*S, H]
{
    __shared__ ushort_t Kl[2][4096];     // [buf][64 rows x 64 elem] 8KB each
    __shared__ ushort_t Vl[2][4096];
    __shared__ ushort_t PlA[4][16 * 72]; // per-wave P^T slabs
    __shared__ ushort_t PlB[4][16 * 72];

    const int tid  = threadIdx.x;
    const int lane = tid & 63;
    const int wave = tid >> 6;
    const int li   = lane & 15;   // frag idx | C/D col (= q index)
    const int lq   = lane >> 4;   // quad
    const int blk  = blockIdx.x;
    const int xcd = blk & 7;
    const int jj  = blk >> 3;            // 0..127
    const int bh  = xcd * 8 + (jj & 7);  // 0..63
    const int pp  = jj >> 3;             // 0..15
    const int pr  = pp * 4 + wave;       // 0..63
    const int h   = bh & (NH - 1);
    const int b   = bh >> 4;
    const int prow = lq * 4;

    const int q0a = pr * 16;             // tile A (jmaxA = pp)
    const int q0b = (127 - pr) * 16;     // tile B (jmaxB = 31-pp)
    const int qrowA = q0a + li;
    const int qrowB = q0b + li;
    const int jmaxB = 31 - pp;

    const size_t bSEQ = (size_t)b * SEQ;
    const int    hoff = h * DH;

    const int srow = tid >> 3;
    const int scs8 = ((tid & 7) ^ (srow & 7)) * 8;   // swizzled chunk * 8 elems

    const int fr0 = li * 64 + ((lq ^ (li & 7)) * 8);

    ushort_t* pwA = &PlA[wave][0];
    ushort_t* pwB = &PlB[wave][0];

    const float* mbase = mask + bSEQ + prow;   // padding mask, indexed by key

    const size_t qaA = (bSEQ + qrowA) * HID + hoff + lq * 8;
    const size_t qaB = (bSEQ + qrowB) * HID + hoff + lq * 8;
    const bf16x8 qfA0 = *(const bf16x8*)&Qp[qaA];
    const bf16x8 qfA1 = *(const bf16x8*)&Qp[qaA + 32];
    const bf16x8 qfB0 = *(const bf16x8*)&Qp[qaB];
    const bf16x8 qfB1 = *(const bf16x8*)&Qp[qaB + 32];

    f32x4 oaA[4], oaB[4];
#pragma unroll
    for (int nt = 0; nt < 4; nt++) {
        oaA[nt] = (f32x4){0.f, 0.f, 0.f, 0.f};
        oaB[nt] = (f32x4){0.f, 0.f, 0.f, 0.f};
    }
    float mA = -1e30f, lA = 0.f, mB = -1e30f, lB = 0.f;

    auto STAGE = [&](int js, int bs) {
        const size_t k0s = (size_t)js * 64;
        const ushort_t* kg = Kp + (bSEQ + k0s + srow) * HID + hoff + scs8;
        ushort_t* kl = &Kl[bs][wave * 512];
        gload16(kg, kl);
        gload16(kg + (size_t)32 * HID, kl + 2048);
        const ushort_t* vg = Vt + (size_t)(hoff + srow) * MTOT + bSEQ + k0s + scs8;
        ushort_t* vl = &Vl[bs][wave * 512];
        gload16(vg, vl);
        gload16(vg + (size_t)32 * MTOT, vl + 2048);
    };

    STAGE(0, 0);
    asm volatile("s_waitcnt vmcnt(0)" ::: "memory");
    __builtin_amdgcn_s_barrier();

    for (int j = 0; j <= jmaxB; ++j) {
        const int  k0  = j * 64;
        const int  bs  = j & 1;
        const bool doA = (j <= pp);          // block-uniform

        f32x4 mk[4];
#pragma unroll
        for (int nt = 0; nt < 4; nt++)
            mk[nt] = *(const f32x4*)&mbase[k0 + nt * 16];
        __builtin_amdgcn_sched_barrier(0);

        if (j < jmaxB) STAGE(j + 1, bs ^ 1);   // issue-early, consumed next iter
        __builtin_amdgcn_sched_barrier(0);

        bf16x8 kf[4][2];
#pragma unroll
        for (int nt = 0; nt < 4; nt++) {
            const int eo = nt * 1024 + fr0;
            kf[nt][0] = *(const bf16x8*)&Kl[bs][eo];
            kf[nt][1] = *(const bf16x8*)&Kl[bs][eo ^ 32];
        }

        f32x4 saA[4], saB[4];
        __builtin_amdgcn_s_setprio(1);
#pragma unroll
        for (int nt = 0; nt < 4; nt++) {
            f32x4 a = (f32x4){0.f, 0.f, 0.f, 0.f};
            a = __builtin_amdgcn_mfma_f32_16x16x32_bf16(kf[nt][0], qfB0, a, 0, 0, 0);
            a = __builtin_amdgcn_mfma_f32_16x16x32_bf16(kf[nt][1], qfB1, a, 0, 0, 0);
            saB[nt] = a;
        }
        if (doA) {
#pragma unroll
            for (int nt = 0; nt < 4; nt++) {
                f32x4 a = (f32x4){0.f, 0.f, 0.f, 0.f};
                a = __builtin_amdgcn_mfma_f32_16x16x32_bf16(kf[nt][0], qfA0, a, 0, 0, 0);
                a = __builtin_amdgcn_mfma_f32_16x16x32_bf16(kf[nt][1], qfA1, a, 0, 0, 0);
                saA[nt] = a;
            }
        }
        __builtin_amdgcn_s_setprio(0);

        float sB[4][4];
#pragma unroll
        for (int nt = 0; nt < 4; nt++)
#pragma unroll
            for (int r = 0; r < 4; r++) {
                const float v = saB[nt][r] * 0.125f;
                sB[nt][r] = (mk[nt][r] == 0.f) ? FILLV : v;
            }
        if (k0 + 63 > q0b) {
#pragma unroll
            for (int nt = 0; nt < 4; nt++)
#pragma unroll
                for (int r = 0; r < 4; r++) {
                    const int kpos = k0 + nt * 16 + prow + r;
                    sB[nt][r] = (kpos > qrowB) ? FILLV : sB[nt][r];
                }
        }
        float pmB = fmaxf(fmaxf(sB[0][0], sB[0][1]), fmaxf(sB[0][2], sB[0][3]));
#pragma unroll
        for (int nt = 1; nt < 4; nt++)
            pmB = fmaxf(pmB, fmaxf(fmaxf(sB[nt][0], sB[nt][1]),
                                   fmaxf(sB[nt][2], sB[nt][3])));
        pmB = fmaxf(pmB, __shfl_xor(pmB, 16));
        pmB = fmaxf(pmB, __shfl_xor(pmB, 32));
        const float mnB = fmaxf(mB, pmB);
        const float alB = __expf(mB - mnB);
        mB = mnB;
        float psB = 0.f;
#pragma unroll
        for (int nt = 0; nt < 4; nt++) {
            const float p0 = __expf(sB[nt][0] - mnB);
            const float p1 = __expf(sB[nt][1] - mnB);
            const float p2 = __expf(sB[nt][2] - mnB);
            const float p3 = __expf(sB[nt][3] - mnB);
            psB += (p0 + p1) + (p2 + p3);
            ushort4 pk;
            pk.x = f2bf(p0); pk.y = f2bf(p1); pk.z = f2bf(p2); pk.w = f2bf(p3);
            *(ushort4*)&pwB[li * 72 + nt * 16 + prow] = pk;
        }
        psB += __shfl_xor(psB, 16);
        psB += __shfl_xor(psB, 32);
        lB = lB * alB + psB;

        float alA = 1.f;
        if (doA) {
            float sA[4][4];
#pragma unroll
            for (int nt = 0; nt < 4; nt++)
#pragma unroll
                for (int r = 0; r < 4; r++) {
                    const float v = saA[nt][r] * 0.125f;
                    sA[nt][r] = (mk[nt][r] == 0.f) ? FILLV : v;
                }
            if (k0 + 63 > q0a) {
#pragma unroll
                for (int nt = 0; nt < 4; nt++)
#pragma unroll
                    for (int r = 0; r < 4; r++) {
                        const int kpos = k0 + nt * 16 + prow + r;
                        sA[nt][r] = (kpos > qrowA) ? FILLV : sA[nt][r];
                    }
            }
            float pmA = fmaxf(fmaxf(sA[0][0], sA[0][1]), fmaxf(sA[0][2], sA[0][3]));
#pragma unroll
            for (int nt = 1; nt < 4; nt++)
                pmA = fmaxf(pmA, fmaxf(fmaxf(sA[nt][0], sA[nt][1]),
                                       fmaxf(sA[nt][2], sA[nt][3])));
            pmA = fmaxf(pmA, __shfl_xor(pmA, 16));
            pmA = fmaxf(pmA, __shfl_xor(pmA, 32));
            const float mnA = fmaxf(mA, pmA);
            alA = __expf(mA - mnA);
            mA = mnA;
            float psA = 0.f;
#pragma unroll
            for (int nt = 0; nt < 4; nt++) {
                const float p0 = __expf(sA[nt][0] - mnA);
                const float p1 = __expf(sA[nt][1] - mnA);
                const float p2 = __expf(sA[nt][2] - mnA);
                const float p3 = __expf(sA[nt][3] - mnA);
                psA += (p0 + p1) + (p2 + p3);
                ushort4 pk;
                pk.x = f2bf(p0); pk.y = f2bf(p1); pk.z = f2bf(p2); pk.w = f2bf(p3);
                *(ushort4*)&pwA[li * 72 + nt * 16 + prow] = pk;
            }
            psA += __shfl_xor(psA, 16);
            psA += __shfl_xor(psA, 32);
            lA = lA * alA + psA;
        }

        const bf16x8 pfB0 = *(const bf16x8*)&pwB[li * 72 + lq * 8];
        const bf16x8 pfB1 = *(const bf16x8*)&pwB[li * 72 + 32 + lq * 8];
        bf16x8 vf[4][2];
#pragma unroll
        for (int nt = 0; nt < 4; nt++) {
            const int eo = nt * 1024 + fr0;
            vf[nt][0] = *(const bf16x8*)&Vl[bs][eo];
            vf[nt][1] = *(const bf16x8*)&Vl[bs][eo ^ 32];
        }

        __builtin_amdgcn_s_setprio(1);
#pragma unroll
        for (int nt = 0; nt < 4; nt++) {
            f32x4 o = oaB[nt];
#pragma unroll
            for (int r = 0; r < 4; r++) o[r] *= alB;
            o = __builtin_amdgcn_mfma_f32_16x16x32_bf16(vf[nt][0], pfB0, o, 0, 0, 0);
            o = __builtin_amdgcn_mfma_f32_16x16x32_bf16(vf[nt][1], pfB1, o, 0, 0, 0);
            oaB[nt] = o;
        }
        __builtin_amdgcn_s_setprio(0);
        if (doA) {
            const bf16x8 pfA0 = *(const bf16x8*)&pwA[li * 72 + lq * 8];
            const bf16x8 pfA1 = *(const bf16x8*)&pwA[li * 72 + 32 + lq * 8];
            __builtin_amdgcn_s_setprio(1);
#pragma unroll
            for (int nt = 0; nt < 4; nt++) {
                f32x4 o = oaA[nt];
#pragma unroll
                for (int r = 0; r < 4; r++) o[r] *= alA;
                o = __builtin_amdgcn_mfma_f32_16x16x32_bf16(vf[nt][0], pfA0, o, 0, 0, 0);
                o = __builtin_amdgcn_mfma_f32_16x16x32_bf16(vf[nt][1], pfA1, o, 0, 0, 0);
                oaA[nt] = o;
            }
            __builtin_amdgcn_s_setprio(0);
        }

        // single end-of-iter sync: next tile staged + all reads of buf bs done
        __builtin_amdgcn_sched_barrier(0);
        asm volatile("s_waitcnt vmcnt(0)" ::: "memory");
        __builtin_amdgcn_s_barrier();
    }

    {
        const float linv = 1.f / lB;
        const size_t obase = (bSEQ + qrowB) * HID + hoff + prow;
#pragma unroll
        for (int nt = 0; nt < 4; nt++) {
            ushort4 ov;
            ov.x = f2bf(oaB[nt][0] * linv);
            ov.y = f2bf(oaB[nt][1] * linv);
            ov.z = f2bf(oaB[nt][2] * linv);
            ov.w = f2bf(oaB[nt][3] * linv);
            *(ushort4*)&Op[obase + nt * 16] = ov;
        }
    }
    {
        const float linv = 1.f / lA;
        const size_t obase = (bSEQ + qrowA) * HID + hoff + prow;
#pragma unroll
        for (int nt = 0; nt < 4; nt++) {
            ushort4 ov;
            ov.x = f2bf(oaA[nt][0] * linv);
            ov.y = f2bf(oaA[nt][1] * linv);
            ov.z = f2bf(oaA[nt][2] * linv);
            ov.w = f2bf(oaA[nt][3] * linv);
            *(ushort4*)&Op[obase + nt * 16] = ov;
        }
    }
}

// ---------------------------------------------------------------------------
extern "C" void kernel_launch(void* const* d_in, const int* in_sizes, int n_in,
                              void* d_out, int out_size, void* d_ws, size_t ws_size,
                              hipStream_t stream) {
    const float* query = (const float*)d_in[0];
    const float* key   = (const float*)d_in[1];
    const float* value = (const float*)d_in[2];
    const float* mask  = (const float*)d_in[3];
    const float* Wq    = (const float*)d_in[4];
    const float* bq    = (const float*)d_in[5];
    const float* Wk    = (const float*)d_in[6];
    const float* bk    = (const float*)d_in[7];
    const float* Wv    = (const float*)d_in[8];
    const float* bv    = (const float*)d_in[9];
    const float* Wo    = (const float*)d_in[10];
    const float* bo    = (const float*)d_in[11];

    // workspace (bf16): 7 activation-size buffers + 4 weight buffers ≈ 125.5 MB
    const size_t eA = (size_t)MTOT * HID;
    const size_t eW = (size_t)HID * HID;
    ushort_t* qb  = (ushort_t*)d_ws;
    ushort_t* kb  = qb  + eA;
    ushort_t* vb  = kb  + eA;
    ushort_t* Qp  = vb  + eA;
    ushort_t* Kp  = Qp  + eA;
    ushort_t* Vtb = Kp  + eA;   // [H, B*S]
    ushort_t* Op  = Vtb + eA;
    ushort_t* wqb = Op  + eA;   // wqb,wkb,wvb,wob contiguous
    ushort_t* wkb = wqb + eW;
    ushort_t* wvb = wkb + eW;
    ushort_t* wob = wvb + eW;

    // fused casts: 2 launches (dests contiguous; seg math is pow-2)
    cast3_act<<<3 * N4A / 256, 256, 0, stream>>>(query, key, value, qb);
    cast4_w  <<<4 * N4W / 256, 256, 0, stream>>>(Wq, Wk, Wv, Wo, wqb);

    // fused QKV projections: 1536 blocks
    qkv_gemm<<<dim3(512, 1, 3), 256, 0, stream>>>(
        qb, kb, wvb, wqb, wkb, vb, bq, bk, bv, Qp, Kp, Vtb);

    // flash attention: 1024 blocks, 4 waves each, XCD-local (b,h)
    attn_mfma<<<(BATCH * NH * 64) / 4, 256, 0, stream>>>(Qp, Kp, Vtb, mask, Op);

    // O-projection (fp32 out)
    dim3 gg(HID / 128, MTOT / 128);   // (8, 64)
    gemm_o<<<gg, 256, 0, stream>>>(Op, wob, bo, (float*)d_out, MTOT, HID, HID);
}

// Round 8
// 383.239 us; speedup vs baseline: 2.4253x; 1.0094x over previous
//
#include <hip/hip_runtime.h>
#include <hip/hip_bf16.h>
#include <math.h>

// Problem constants: B=4, S=2048, H=1024, nh=16, dh=64.
#define BATCH 4
#define SEQ   2048
#define HID   1024
#define NH    16
#define DH    64
#define MTOT  (BATCH * SEQ)   // 8192
#define FILLV (-1e13f)
#define N4A   (MTOT * HID / 4)   // 2^21 float4-groups per activation buffer
#define N4W   (HID * HID / 4)    // 2^18 per weight buffer

typedef unsigned short ushort_t;
typedef short bf16x8 __attribute__((ext_vector_type(8)));
typedef float f32x4  __attribute__((ext_vector_type(4)));

__device__ __forceinline__ float bf2f(ushort_t u) {
    return __uint_as_float(((unsigned int)u) << 16);
}
__device__ __forceinline__ ushort_t f2bf(float f) {
    union { __hip_bfloat16 h; ushort_t u; } cv;
    cv.h = __float2bfloat16(f);
    return cv.u;
}

// async global->LDS, 16B per lane; LDS dest = wave-uniform base + lane*16
__device__ __forceinline__ void gload16(const void* g, void* l) {
    __builtin_amdgcn_global_load_lds(
        (const __attribute__((address_space(1))) unsigned int*)g,
        (__attribute__((address_space(3))) unsigned int*)l, 16, 0, 0);
}

__device__ __forceinline__ ushort4 cvt4(const float4 v) {
    ushort4 o;
    o.x = f2bf(v.x); o.y = f2bf(v.y); o.z = f2bf(v.z); o.w = f2bf(v.w);
    return o;
}

// ---------------------------------------------------------------------------
// fused fp32->bf16 casts
// ---------------------------------------------------------------------------
__global__ __launch_bounds__(256) void cast3_act(
    const float* __restrict__ s0, const float* __restrict__ s1,
    const float* __restrict__ s2, ushort_t* __restrict__ dst)
{
    const int i   = blockIdx.x * 256 + threadIdx.x;      // < 3*N4A
    const int seg = i >> 21;                             // block-uniform
    const int off = i & (N4A - 1);
    const float* s = (seg == 0) ? s0 : (seg == 1) ? s1 : s2;
    ((ushort4*)dst)[i] = cvt4(((const float4*)s)[off]);
}

__global__ __launch_bounds__(256) void cast4_w(
    const float* __restrict__ s0, const float* __restrict__ s1,
    const float* __restrict__ s2, const float* __restrict__ s3,
    ushort_t* __restrict__ dst)
{
    const int i   = blockIdx.x * 256 + threadIdx.x;      // < 4*N4W
    const int seg = i >> 18;
    const int off = i & (N4W - 1);
    const float* s = (seg == 0) ? s0 : (seg == 1) ? s1 : (seg == 2) ? s2 : s3;
    ((ushort4*)dst)[i] = cvt4(((const float4*)s)[off]);
}

// ---------------------------------------------------------------------------
// 256x128-tile MFMA GEMM body: Y[M,N] = A[M,1024] @ W[N,1024]^T + bias.
// ROUND-8: r5/r6/r7 A/B-isolated that barrier count is null and 2-deep
// prefetch is +10% -- the residual ~60% idle is geometry (128^2 blocks too
// small: 16 MFMA per wave-iter vs ~1360cyc wall, 8 column-blocks re-stream
// A-panels). This keeps the VERIFIED r7 loop skeleton (BK=32, 3-slot LDS,
// 2-deep counted vmcnt, one barrier/iter, linear-packed LDS = 0 conflicts)
// and scales the block: 256x128 tile, 8 waves (4m x 2n, 64x64 per wave).
//  - staged bytes/output x0.75 (B amortized over 256 rows)
//  - 2 blocks/CU x 8 waves = 16 waves/CU (LDS 72KB; VGPR capped 128 via
//    __launch_bounds__(512,4); live set ~ acc64+frags32+addr ~115 -> fits)
// Staging map: wave w stages A-subtiles {2w,2w+1}, B-subtile {w};
// LDS [subtile][lane*8] holds row m0+sub*16+li, k = k0+lq*8 -> frag reads
// are per-wave linear 1KB slabs (conflict-free), gload16 dest uniform.
// ---------------------------------------------------------------------------
template <bool OUT_BF16, bool BIAS_ROW>
__device__ __forceinline__ void gemm_body_256x128(
    const ushort_t* __restrict__ A,
    const ushort_t* __restrict__ W,
    const float* __restrict__ bias,
    void* __restrict__ Yv,
    int Nz, int m0, int n0,
    ushort_t (*Al)[16 * 512], ushort_t (*Bl)[8 * 512])
{
    const int tid  = threadIdx.x;
    const int lane = tid & 63;
    const int wave = tid >> 6;       // 0..7
    const int wm   = wave >> 1;      // 0..3  (64-row slice)
    const int wn   = wave & 1;       // 0..1  (64-col slice)
    const int li   = lane & 15;
    const int lq8  = (lane >> 4) * 8;

    f32x4 acc[4][4];
#pragma unroll
    for (int i = 0; i < 4; i++)
#pragma unroll
        for (int j = 0; j < 4; j++) acc[i][j] = (f32x4){0.f, 0.f, 0.f, 0.f};

    // per-lane global staging bases (k advances by +kk)
    const ushort_t* aS0 = A + (size_t)(m0 + (2 * wave) * 16 + li) * HID + lq8;
    const ushort_t* aS1 = aS0 + (size_t)16 * HID;
    const ushort_t* wS  = W + (size_t)(n0 + wave * 16 + li) * HID + lq8;

    // stage K-chunk kk into slot d: 3 gload16 per thread
    auto STAGE = [&](int kk, int d) {
        gload16(aS0 + kk, &Al[d][(2 * wave) * 512]);
        gload16(aS1 + kk, &Al[d][(2 * wave + 1) * 512]);
        gload16(wS + kk,  &Bl[d][wave * 512]);
    };

    const int nk = HID >> 5;   // 32
    STAGE(0, 0);
    STAGE(32, 1);

    for (int kt = 0; kt < nk; ++kt) {
        const int d = kt % 3;
        if (kt + 1 < nk) {
            // outstanding: stage(kt)=3 oldest + stage(kt+1)=3 -> wait to <=3
            asm volatile("s_waitcnt vmcnt(3)" ::: "memory");
        } else {
            asm volatile("s_waitcnt vmcnt(0)" ::: "memory");
        }
        __builtin_amdgcn_s_barrier();
        __builtin_amdgcn_sched_barrier(0);
        if (kt + 2 < nk) STAGE((kt + 2) << 5, (kt + 2) % 3);
        __builtin_amdgcn_sched_barrier(0);

        bf16x8 af[4], bf[4];
#pragma unroll
        for (int i = 0; i < 4; i++)
            af[i] = *(const bf16x8*)&Al[d][(wm * 4 + i) * 512 + lane * 8];
#pragma unroll
        for (int j = 0; j < 4; j++)
            bf[j] = *(const bf16x8*)&Bl[d][(wn * 4 + j) * 512 + lane * 8];
        __builtin_amdgcn_s_setprio(1);
#pragma unroll
        for (int i = 0; i < 4; i++)
#pragma unroll
            for (int j = 0; j < 4; j++)
                acc[i][j] = __builtin_amdgcn_mfma_f32_16x16x32_bf16(
                    af[i], bf[j], acc[i][j], 0, 0, 0);
        __builtin_amdgcn_s_setprio(0);
        // no trailing barrier: next iter's top barrier orders the overwrite
        // (a wave's ds_reads are lgkm-complete before it reaches that barrier)
    }

    const int orow = (lane >> 4) * 4;
#pragma unroll
    for (int i = 0; i < 4; i++) {
#pragma unroll
        for (int j = 0; j < 4; j++) {
            const int col = n0 + wn * 64 + j * 16 + li;
#pragma unroll
            for (int r = 0; r < 4; r++) {
                const int row = m0 + wm * 64 + i * 16 + orow + r;
                const float bvv = BIAS_ROW ? bias[row] : bias[col];
                const float v = acc[i][j][r] + bvv;
                if (OUT_BF16)
                    ((ushort_t*)Yv)[(size_t)row * Nz + col] = f2bf(v);
                else
                    ((float*)Yv)[(size_t)row * Nz + col] = v;
            }
        }
    }
}

// FUSED QKV projections: 3 z-slices x 256 blocks of 512 threads.
//  z=0: Qp = qb@Wq^T + bq (col bias); z=1: Kp; z=2: Vtb = wvb@vb^T + bv (row)
__global__ __launch_bounds__(512, 4) void qkv_gemm(
    const ushort_t* __restrict__ A0, const ushort_t* __restrict__ A1,
    const ushort_t* __restrict__ A2,
    const ushort_t* __restrict__ W0, const ushort_t* __restrict__ W1,
    const ushort_t* __restrict__ W2,
    const float* __restrict__ b0, const float* __restrict__ b1,
    const float* __restrict__ b2,
    ushort_t* __restrict__ Y0, ushort_t* __restrict__ Y1,
    ushort_t* __restrict__ Y2)
{
    __shared__ ushort_t Al[3][16 * 512];   // 48KB
    __shared__ ushort_t Bl[3][8 * 512];    // 24KB

    const int z = blockIdx.z;
    const ushort_t* A    = (z == 0) ? A0 : (z == 1) ? A1 : A2;
    const ushort_t* W    = (z == 0) ? W0 : (z == 1) ? W1 : W2;
    const float*    bias = (z == 0) ? b0 : (z == 1) ? b1 : b2;
    ushort_t*       Y    = (z == 0) ? Y0 : (z == 1) ? Y1 : Y2;
    const int Nz = (z == 2) ? MTOT : HID;
    const int gx = Nz >> 7;                // n-blocks: 8 or 64

    // XCD-chunked bijective swizzle (256 blocks/slice, 32/XCD)
    const int flat = blockIdx.x;
    const int fl2  = (flat & 7) * 32 + (flat >> 3);
    const int bx   = fl2 % gx;
    const int by   = fl2 / gx;

    if (z == 2)
        gemm_body_256x128<true, true>(A, W, bias, Y, Nz, by * 256, bx * 128, Al, Bl);
    else
        gemm_body_256x128<true, false>(A, W, bias, Y, Nz, by * 256, bx * 128, Al, Bl);
}

// O-projection (fp32 out): 256 blocks of 512 threads.
__global__ __launch_bounds__(512, 4) void gemm_o(
    const ushort_t* __restrict__ A,   // [8192,1024] bf16
    const ushort_t* __restrict__ W,   // [1024,1024] bf16
    const float*    __restrict__ bias,
    float* __restrict__ Yv)           // [8192,1024] fp32
{
    __shared__ ushort_t Al[3][16 * 512];
    __shared__ ushort_t Bl[3][8 * 512];

    const int flat = blockIdx.x;
    const int fl2  = (flat & 7) * 32 + (flat >> 3);
    const int bx   = fl2 % 8;
    const int by   = fl2 / 8;

    gemm_body_256x128<false, false>(A, W, bias, Yv, HID, by * 256, bx * 128, Al, Bl);
}

// ---------------------------------------------------------------------------
// MFMA flash attention v4 (verified rounds 3-7, ~107 us). UNCHANGED.
// ---------------------------------------------------------------------------
__global__ __launch_bounds__(256, 2) void attn_mfma(
    const ushort_t* __restrict__ Qp,   // [B*S, H]
    const ushort_t* __restrict__ Kp,   // [B*S, H]
    const ushort_t* __restrict__ Vt,   // [H, B*S]
    const float*    __restrict__ mask, // [B, S] over key positions
    ushort_t* __restrict__ Op)         // [B*S, H]
{
    __shared__ ushort_t Kl[2][4096];     // [buf][64 rows x 64 elem] 8KB each
    __shared__ ushort_t Vl[2][4096];
    __shared__ ushort_t PlA[4][16 * 72]; // per-wave P^T slabs
    __shared__ ushort_t PlB[4][16 * 72];

    const int tid  = threadIdx.x;
    const int lane = tid & 63;
    const int wave = tid >> 6;
    const int li   = lane & 15;   // frag idx | C/D col (= q index)
    const int lq   = lane >> 4;   // quad
    const int blk  = blockIdx.x;
    const int xcd = blk & 7;
    const int jj  = blk >> 3;            // 0..127
    const int bh  = xcd * 8 + (jj & 7);  // 0..63
    const int pp  = jj >> 3;             // 0..15
    const int pr  = pp * 4 + wave;       // 0..63
    const int h   = bh & (NH - 1);
    const int b   = bh >> 4;
    const int prow = lq * 4;

    const int q0a = pr * 16;             // tile A (jmaxA = pp)
    const int q0b = (127 - pr) * 16;     // tile B (jmaxB = 31-pp)
    const int qrowA = q0a + li;
    const int qrowB = q0b + li;
    const int jmaxB = 31 - pp;

    const size_t bSEQ = (size_t)b * SEQ;
    const int    hoff = h * DH;

    const int srow = tid >> 3;
    const int scs8 = ((tid & 7) ^ (srow & 7)) * 8;   // swizzled chunk * 8 elems

    const int fr0 = li * 64 + ((lq ^ (li & 7)) * 8);

    ushort_t* pwA = &PlA[wave][0];
    ushort_t* pwB = &PlB[wave][0];

    const float* mbase = mask + bSEQ + prow;   // padding mask, indexed by key

    const size_t qaA = (bSEQ + qrowA) * HID + hoff + lq * 8;
    const size_t qaB = (bSEQ + qrowB) * HID + hoff + lq * 8;
    const bf16x8 qfA0 = *(const bf16x8*)&Qp[qaA];
    const bf16x8 qfA1 = *(const bf16x8*)&Qp[qaA + 32];
    const bf16x8 qfB0 = *(const bf16x8*)&Qp[qaB];
    const bf16x8 qfB1 = *(const bf16x8*)&Qp[qaB + 32];

    f32x4 oaA[4], oaB[4];
#pragma unroll
    for (int nt = 0; nt < 4; nt++) {
        oaA[nt] = (f32x4){0.f, 0.f, 0.f, 0.f};
        oaB[nt] = (f32x4){0.f, 0.f, 0.f, 0.f};
    }
    float mA = -1e30f, lA = 0.f, mB = -1e30f, lB = 0.f;

    auto STAGE = [&](int js, int bs) {
        const size_t k0s = (size_t)js * 64;
        const ushort_t* kg = Kp + (bSEQ + k0s + srow) * HID + hoff + scs8;
        ushort_t* kl = &Kl[bs][wave * 512];
        gload16(kg, kl);
        gload16(kg + (size_t)32 * HID, kl + 2048);
        const ushort_t* vg = Vt + (size_t)(hoff + srow) * MTOT + bSEQ + k0s + scs8;
        ushort_t* vl = &Vl[bs][wave * 512];
        gload16(vg, vl);
        gload16(vg + (size_t)32 * MTOT, vl + 2048);
    };

    STAGE(0, 0);
    asm volatile("s_waitcnt vmcnt(0)" ::: "memory");
    __builtin_amdgcn_s_barrier();

    for (int j = 0; j <= jmaxB; ++j) {
        const int  k0  = j * 64;
        const int  bs  = j & 1;
        const bool doA = (j <= pp);          // block-uniform

        f32x4 mk[4];
#pragma unroll
        for (int nt = 0; nt < 4; nt++)
            mk[nt] = *(const f32x4*)&mbase[k0 + nt * 16];
        __builtin_amdgcn_sched_barrier(0);

        if (j < jmaxB) STAGE(j + 1, bs ^ 1);   // issue-early, consumed next iter
        __builtin_amdgcn_sched_barrier(0);

        bf16x8 kf[4][2];
#pragma unroll
        for (int nt = 0; nt < 4; nt++) {
            const int eo = nt * 1024 + fr0;
            kf[nt][0] = *(const bf16x8*)&Kl[bs][eo];
            kf[nt][1] = *(const bf16x8*)&Kl[bs][eo ^ 32];
        }

        f32x4 saA[4], saB[4];
        __builtin_amdgcn_s_setprio(1);
#pragma unroll
        for (int nt = 0; nt < 4; nt++) {
            f32x4 a = (f32x4){0.f, 0.f, 0.f, 0.f};
            a = __builtin_amdgcn_mfma_f32_16x16x32_bf16(kf[nt][0], qfB0, a, 0, 0, 0);
            a = __builtin_amdgcn_mfma_f32_16x16x32_bf16(kf[nt][1], qfB1, a, 0, 0, 0);
            saB[nt] = a;
        }
        if (doA) {
#pragma unroll
            for (int nt = 0; nt < 4; nt++) {
                f32x4 a = (f32x4){0.f, 0.f, 0.f, 0.f};
                a = __builtin_amdgcn_mfma_f32_16x16x32_bf16(kf[nt][0], qfA0, a, 0, 0, 0);
                a = __builtin_amdgcn_mfma_f32_16x16x32_bf16(kf[nt][1], qfA1, a, 0, 0, 0);
                saA[nt] = a;
            }
        }
        __builtin_amdgcn_s_setprio(0);

        float sB[4][4];
#pragma unroll
        for (int nt = 0; nt < 4; nt++)
#pragma unroll
            for (int r = 0; r < 4; r++) {
                const float v = saB[nt][r] * 0.125f;
                sB[nt][r] = (mk[nt][r] == 0.f) ? FILLV : v;
            }
        if (k0 + 63 > q0b) {
#pragma unroll
            for (int nt = 0; nt < 4; nt++)
#pragma unroll
                for (int r = 0; r < 4; r++) {
                    const int kpos = k0 + nt * 16 + prow + r;
                    sB[nt][r] = (kpos > qrowB) ? FILLV : sB[nt][r];
                }
        }
        float pmB = fmaxf(fmaxf(sB[0][0], sB[0][1]), fmaxf(sB[0][2], sB[0][3]));
#pragma unroll
        for (int nt = 1; nt < 4; nt++)
            pmB = fmaxf(pmB, fmaxf(fmaxf(sB[nt][0], sB[nt][1]),
                                   fmaxf(sB[nt][2], sB[nt][3])));
        pmB = fmaxf(pmB, __shfl_xor(pmB, 16));
        pmB = fmaxf(pmB, __shfl_xor(pmB, 32));
        const float mnB = fmaxf(mB, pmB);
        const float alB = __expf(mB - mnB);
        mB = mnB;
        float psB = 0.f;
#pragma unroll
        for (int nt = 0; nt < 4; nt++) {
            const float p0 = __expf(sB[nt][0] - mnB);
            const float p1 = __expf(sB[nt][1] - mnB);
            const float p2 = __expf(sB[nt][2] - mnB);
            const float p3 = __expf(sB[nt][3] - mnB);
            psB += (p0 + p1) + (p2 + p3);
            ushort4 pk;
            pk.x = f2bf(p0); pk.y = f2bf(p1); pk.z = f2bf(p2); pk.w = f2bf(p3);
            *(ushort4*)&pwB[li * 72 + nt * 16 + prow] = pk;
        }
        psB += __shfl_xor(psB, 16);
        psB += __shfl_xor(psB, 32);
        lB = lB * alB + psB;

        float alA = 1.f;
        if (doA) {
            float sA[4][4];
#pragma unroll
            for (int nt = 0; nt < 4; nt++)
#pragma unroll
                for (int r = 0; r < 4; r++) {
                    const float v = saA[nt][r] * 0.125f;
                    sA[nt][r] = (mk[nt][r] == 0.f) ? FILLV : v;
                }
            if (k0 + 63 > q0a) {
#pragma unroll
                for (int nt = 0; nt < 4; nt++)
#pragma unroll
                    for (int r = 0; r < 4; r++) {
                        const int kpos = k0 + nt * 16 + prow + r;
                        sA[nt][r] = (kpos > qrowA) ? FILLV : sA[nt][r];
                    }
            }
            float pmA = fmaxf(fmaxf(sA[0][0], sA[0][1]), fmaxf(sA[0][2], sA[0][3]));
#pragma unroll
            for (int nt = 1; nt < 4; nt++)
                pmA = fmaxf(pmA, fmaxf(fmaxf(sA[nt][0], sA[nt][1]),
                                       fmaxf(sA[nt][2], sA[nt][3])));
            pmA = fmaxf(pmA, __shfl_xor(pmA, 16));
            pmA = fmaxf(pmA, __shfl_xor(pmA, 32));
            const float mnA = fmaxf(mA, pmA);
            alA = __expf(mA - mnA);
            mA = mnA;
            float psA = 0.f;
#pragma unroll
            for (int nt = 0; nt < 4; nt++) {
                const float p0 = __expf(sA[nt][0] - mnA);
                const float p1 = __expf(sA[nt][1] - mnA);
                const float p2 = __expf(sA[nt][2] - mnA);
                const float p3 = __expf(sA[nt][3] - mnA);
                psA += (p0 + p1) + (p2 + p3);
                ushort4 pk;
                pk.x = f2bf(p0); pk.y = f2bf(p1); pk.z = f2bf(p2); pk.w = f2bf(p3);
                *(ushort4*)&pwA[li * 72 + nt * 16 + prow] = pk;
            }
            psA += __shfl_xor(psA, 16);
            psA += __shfl_xor(psA, 32);
            lA = lA * alA + psA;
        }

        const bf16x8 pfB0 = *(const bf16x8*)&pwB[li * 72 + lq * 8];
        const bf16x8 pfB1 = *(const bf16x8*)&pwB[li * 72 + 32 + lq * 8];
        bf16x8 vf[4][2];
#pragma unroll
        for (int nt = 0; nt < 4; nt++) {
            const int eo = nt * 1024 + fr0;
            vf[nt][0] = *(const bf16x8*)&Vl[bs][eo];
            vf[nt][1] = *(const bf16x8*)&Vl[bs][eo ^ 32];
        }

        __builtin_amdgcn_s_setprio(1);
#pragma unroll
        for (int nt = 0; nt < 4; nt++) {
            f32x4 o = oaB[nt];
#pragma unroll
            for (int r = 0; r < 4; r++) o[r] *= alB;
            o = __builtin_amdgcn_mfma_f32_16x16x32_bf16(vf[nt][0], pfB0, o, 0, 0, 0);
            o = __builtin_amdgcn_mfma_f32_16x16x32_bf16(vf[nt][1], pfB1, o, 0, 0, 0);
            oaB[nt] = o;
        }
        __builtin_amdgcn_s_setprio(0);
        if (doA) {
            const bf16x8 pfA0 = *(const bf16x8*)&pwA[li * 72 + lq * 8];
            const bf16x8 pfA1 = *(const bf16x8*)&pwA[li * 72 + 32 + lq * 8];
            __builtin_amdgcn_s_setprio(1);
#pragma unroll
            for (int nt = 0; nt < 4; nt++) {
                f32x4 o = oaA[nt];
#pragma unroll
                for (int r = 0; r < 4; r++) o[r] *= alA;
                o = __builtin_amdgcn_mfma_f32_16x16x32_bf16(vf[nt][0], pfA0, o, 0, 0, 0);
                o = __builtin_amdgcn_mfma_f32_16x16x32_bf16(vf[nt][1], pfA1, o, 0, 0, 0);
                oaA[nt] = o;
            }
            __builtin_amdgcn_s_setprio(0);
        }

        // single end-of-iter sync: next tile staged + all reads of buf bs done
        __builtin_amdgcn_sched_barrier(0);
        asm volatile("s_waitcnt vmcnt(0)" ::: "memory");
        __builtin_amdgcn_s_barrier();
    }

    {
        const float linv = 1.f / lB;
        const size_t obase = (bSEQ + qrowB) * HID + hoff + prow;
#pragma unroll
        for (int nt = 0; nt < 4; nt++) {
            ushort4 ov;
            ov.x = f2bf(oaB[nt][0] * linv);
            ov.y = f2bf(oaB[nt][1] * linv);
            ov.z = f2bf(oaB[nt][2] * linv);
            ov.w = f2bf(oaB[nt][3] * linv);
            *(ushort4*)&Op[obase + nt * 16] = ov;
        }
    }
    {
        const float linv = 1.f / lA;
        const size_t obase = (bSEQ + qrowA) * HID + hoff + prow;
#pragma unroll
        for (int nt = 0; nt < 4; nt++) {
            ushort4 ov;
            ov.x = f2bf(oaA[nt][0] * linv);
            ov.y = f2bf(oaA[nt][1] * linv);
            ov.z = f2bf(oaA[nt][2] * linv);
            ov.w = f2bf(oaA[nt][3] * linv);
            *(ushort4*)&Op[obase + nt * 16] = ov;
        }
    }
}

// ---------------------------------------------------------------------------
extern "C" void kernel_launch(void* const* d_in, const int* in_sizes, int n_in,
                              void* d_out, int out_size, void* d_ws, size_t ws_size,
                              hipStream_t stream) {
    const float* query = (const float*)d_in[0];
    const float* key   = (const float*)d_in[1];
    const float* value = (const float*)d_in[2];
    const float* mask  = (const float*)d_in[3];
    const float* Wq    = (const float*)d_in[4];
    const float* bq    = (const float*)d_in[5];
    const float* Wk    = (const float*)d_in[6];
    const float* bk    = (const float*)d_in[7];
    const float* Wv    = (const float*)d_in[8];
    const float* bv    = (const float*)d_in[9];
    const float* Wo    = (const float*)d_in[10];
    const float* bo    = (const float*)d_in[11];

    // workspace (bf16): 7 activation-size buffers + 4 weight buffers ≈ 125.5 MB
    const size_t eA = (size_t)MTOT * HID;
    const size_t eW = (size_t)HID * HID;
    ushort_t* qb  = (ushort_t*)d_ws;
    ushort_t* kb  = qb  + eA;
    ushort_t* vb  = kb  + eA;
    ushort_t* Qp  = vb  + eA;
    ushort_t* Kp  = Qp  + eA;
    ushort_t* Vtb = Kp  + eA;   // [H, B*S]
    ushort_t* Op  = Vtb + eA;
    ushort_t* wqb = Op  + eA;   // wqb,wkb,wvb,wob contiguous
    ushort_t* wkb = wqb + eW;
    ushort_t* wvb = wkb + eW;
    ushort_t* wob = wvb + eW;

    // fused casts: 2 launches (dests contiguous; seg math is pow-2)
    cast3_act<<<3 * N4A / 256, 256, 0, stream>>>(query, key, value, qb);
    cast4_w  <<<4 * N4W / 256, 256, 0, stream>>>(Wq, Wk, Wv, Wo, wqb);

    // fused QKV projections: 3 x 256 blocks of 512 threads (256x128 tiles)
    qkv_gemm<<<dim3(256, 1, 3), 512, 0, stream>>>(
        qb, kb, wvb, wqb, wkb, vb, bq, bk, bv, Qp, Kp, Vtb);

    // flash attention: 1024 blocks, 4 waves each, XCD-local (b,h)
    attn_mfma<<<(BATCH * NH * 64) / 4, 256, 0, stream>>>(Qp, Kp, Vtb, mask, Op);

    // O-projection (fp32 out): 256 blocks of 512 threads
    gemm_o<<<256, 512, 0, stream>>>(Op, wob, bo, (float*)d_out);
}